// Round 4
// baseline (470.411 us; speedup 1.0000x reference)
//
#include <hip/hip_runtime.h>

typedef unsigned short u16;
typedef __bf16 bf16x8 __attribute__((ext_vector_type(8)));
typedef u16   u16x8  __attribute__((ext_vector_type(8)));
typedef u16   u16x4  __attribute__((ext_vector_type(4)));
typedef float f32x4  __attribute__((ext_vector_type(4)));

// packed row layout: per batch, modality rows at OFFS[m], total RPB rows/batch
#define RPB 5084
#define SL0 2048
#define SL1 1024
#define SL2 1500
#define SL3 512

// ---------- helpers ----------
__device__ __forceinline__ u16 f2bf(float f) {
  union { float f; unsigned u; } x; x.f = f;
  unsigned u = x.u;
  u += 0x7fffu + ((u >> 16) & 1u);   // RNE
  return (u16)(u >> 16);
}
__device__ __forceinline__ float bf2f(u16 h) {
  union { unsigned u; float f; } x; x.u = ((unsigned)h) << 16;
  return x.f;
}
// async global->LDS, 16B per lane; dest = wave-uniform base + lane*16
__device__ __forceinline__ void gll16(const u16* g, u16* l) {
  __builtin_amdgcn_global_load_lds(
      (const __attribute__((address_space(1))) void*)g,
      (__attribute__((address_space(3))) void*)l, 16, 0, 0);
}

// LDS chunk layout (all GEMMs): each 16-row x 32-k tile is a 1024B chunk.
// Stage lane s fetches global (row s>>2, k-oct (s&3)^((s>>3)&3)) -> lands at
// chunk_base + s*16. Quad s=4q..4q+3 covers one row's 64B contiguously ->
// full coalescing. Fragment read for lane L (row L&15, oct L>>4) sits at
// u16 offset 32*(L&15) + 8*((L>>4)^(((L&15)>>1)&3)); every 8 consecutive
// read lanes hit 8 distinct bank-quads -> ZERO conflicts (verified r2/r3).

// ---------- fused fp32 -> bf16 conversion, 12 segments, one launch ----------
#define NSEG 12
struct CvtSegs {
  const float* src[NSEG];
  u16*         dst[NSEG];
  int          blk_end[NSEG];
  int          blk_base[NSEG];
};
__global__ __launch_bounds__(256) void cvt_multi(CvtSegs segs) {
  int blk = blockIdx.x, seg = 0;
#pragma unroll
  for (int s = 0; s < NSEG; ++s) if (blk >= segs.blk_end[s]) seg = s + 1;
  const float* src = segs.src[seg];
  u16* dst = segs.dst[seg];
  int i = (blk - segs.blk_base[seg]) * 1024 + threadIdx.x * 4;
  f32x4 v = *(const f32x4*)(src + i);
  u16x4 o;
  o[0] = f2bf(v[0]); o[1] = f2bf(v[1]); o[2] = f2bf(v[2]); o[3] = f2bf(v[3]);
  *(u16x4*)(dst + i) = o;
}

// ---------- m97-style bf16 GEMM via global_load_lds (output GEMM) ----------
template<int STORE_F32>
__global__ __launch_bounds__(256) void gemm_lds(
    const u16* __restrict__ A,
    const u16* __restrict__ B0, const u16* __restrict__ B1, const u16* __restrict__ B2,
    const float* __restrict__ c0, const float* __restrict__ c1, const float* __restrict__ c2,
    void* __restrict__ Cout, int Mr, int K, int ldc)
{
  __shared__ u16 lA0[128 * 32], lA1[128 * 32];
  __shared__ u16 lB0[128 * 32], lB1[128 * 32];
  const int tid  = threadIdx.x;
  const int lane = tid & 63;
  const int wave = tid >> 6;
  const int wr   = (wave >> 1) * 64;
  const int wc   = (wave & 1) * 64;
  const int row0 = blockIdx.y * 128;

  const int wsel = blockIdx.x >> 3;
  const int colL = (blockIdx.x & 7) * 128;
  const u16*   Bw   = (wsel == 0) ? B0 : (wsel == 1) ? B1 : B2;
  const float* bias = (wsel == 0) ? c0 : (wsel == 1) ? c1 : c2;

  // stage mapping: quad-contiguous global, XOR-permuted octet within quad
  const int srow = lane >> 2;
  const int soct = (((lane & 3) ^ ((lane >> 3) & 3))) << 3;
  int ra0 = row0 + wave * 32 + srow;      if (ra0 >= Mr) ra0 = Mr - 1;
  int ra1 = row0 + wave * 32 + srow + 16; if (ra1 >= Mr) ra1 = Mr - 1;
  const u16* pA0 = A + (size_t)ra0 * K + soct;
  const u16* pA1 = A + (size_t)ra1 * K + soct;
  const u16* pB0 = Bw + (size_t)(colL + wave * 32 + srow) * K + soct;
  const u16* pB1 = pB0 + (size_t)16 * K;
  u16* dA0a = &lA0[(wave * 32) * 32];      u16* dA1a = &lA0[(wave * 32 + 16) * 32];
  u16* dA0b = &lA1[(wave * 32) * 32];      u16* dA1b = &lA1[(wave * 32 + 16) * 32];
  u16* dB0a = &lB0[(wave * 32) * 32];      u16* dB1a = &lB0[(wave * 32 + 16) * 32];
  u16* dB0b = &lB1[(wave * 32) * 32];      u16* dB1b = &lB1[(wave * 32 + 16) * 32];

  f32x4 acc[4][4];
#pragma unroll
  for (int i = 0; i < 4; ++i)
#pragma unroll
    for (int j = 0; j < 4; ++j) acc[i][j] = f32x4{0.f, 0.f, 0.f, 0.f};

  // fragment read offset within a 512-u16 chunk (conflict-free)
  const int fr  = lane & 15;
  const int fo  = lane >> 4;
  const int lrd = fr * 32 + (((fo ^ ((fr >> 1) & 3))) << 3);
  const int ca  = (wr >> 4) * 512;   // A chunk base (u16) for this wave
  const int cbb = (wc >> 4) * 512;   // B chunk base (u16)

  for (int k0 = 0; k0 < K; k0 += 64) {
    __syncthreads();
    gll16(pA0 + k0, dA0a);       gll16(pA1 + k0, dA1a);
    gll16(pB0 + k0, dB0a);       gll16(pB1 + k0, dB1a);
    gll16(pA0 + k0 + 32, dA0b);  gll16(pA1 + k0 + 32, dA1b);
    gll16(pB0 + k0 + 32, dB0b);  gll16(pB1 + k0 + 32, dB1b);
    __syncthreads();

    bf16x8 af[4], bfr[4];
#pragma unroll
    for (int j = 0; j < 4; ++j)
      bfr[j] = *(const bf16x8*)&lB0[cbb + j * 512 + lrd];
#pragma unroll
    for (int i = 0; i < 4; ++i)
      af[i] = *(const bf16x8*)&lA0[ca + i * 512 + lrd];
#pragma unroll
    for (int i = 0; i < 4; ++i)
#pragma unroll
      for (int j = 0; j < 4; ++j)
        acc[i][j] = __builtin_amdgcn_mfma_f32_16x16x32_bf16(af[i], bfr[j], acc[i][j], 0, 0, 0);
#pragma unroll
    for (int j = 0; j < 4; ++j)
      bfr[j] = *(const bf16x8*)&lB1[cbb + j * 512 + lrd];
#pragma unroll
    for (int i = 0; i < 4; ++i)
      af[i] = *(const bf16x8*)&lA1[ca + i * 512 + lrd];
#pragma unroll
    for (int i = 0; i < 4; ++i)
#pragma unroll
      for (int j = 0; j < 4; ++j)
        acc[i][j] = __builtin_amdgcn_mfma_f32_16x16x32_bf16(af[i], bfr[j], acc[i][j], 0, 0, 0);
  }

  // epilogue: C/D layout col = lane&15, row = (lane>>4)*4 + reg  [m89/m91]
  const int fc = lane & 15;
  const int rq = (lane >> 4) * 4;
#pragma unroll
  for (int i = 0; i < 4; ++i) {
#pragma unroll
    for (int j = 0; j < 4; ++j) {
      const int cl = wc + j * 16 + fc;
      const float badd = bias[colL + cl];
      const int gc = blockIdx.x * 128 + cl;
#pragma unroll
      for (int reg = 0; reg < 4; ++reg) {
        int gr = row0 + wr + i * 16 + rq + reg;
        if (gr < Mr) {
          float v = acc[i][j][reg] + badd;
          if (STORE_F32) ((float*)Cout)[(size_t)gr * ldc + gc] = v;
          else           ((u16*)Cout)[(size_t)gr * ldc + gc] = f2bf(v);
        }
      }
    }
  }
}

// ---------- QKV GEMM: 256^2 tile, BK=64, 8-phase schedule (T2+T3+T4+T5) ----------
// 8 waves (2M x 4N), per-wave C = 128x64. LDS = 2 dbuf slots x (A 32KB + B 32KB)
// = 128 KiB, as [slot][mat][ks(32-k slice)][rowgrp(16 rows)][512] chunks.
// Per iteration = 2 K-tiles (BK=64 each), 8 phases:
//   P1: read Q00(s0) 12x ds_read | stage A(t+1)h1 [i>0] | lgkm(8),bar,lgkm(0) | 16 MFMA
//   P2: read B n2-3 (4)          |                      | bar,lgkm(0)         | 16 MFMA
//   P3: read A m4-7 (8)          | stage B(t+2)h0       | bar,lgkm(0)         | 16 MFMA
//   P4: no reads                 | stage B(t+2)h1,A(t+2)h0 | VMCNT(6),bar     | 16 MFMA
//   P5..P8: same for K-tile t+1 (slot 1), staging A(t+2)h1, B(t+3)h0/h1, A(t+3)h0
// vmcnt(6) at P4/P8 only (3 half-tiles x 2 loads in flight). Per-wave ledger
// verified: W4 certifies tile 2i+1 complete (needed at P5), W8 certifies tile
// 2i+2 (needed at next P1). WAR: each stage targets regions whose last reader
// phase precedes it (B-half free after 2 phases, A-half after 3). Tail iters
// issue clamped dummy re-stages to keep the vmcnt count uniform.
__global__ __launch_bounds__(512, 2) void gemm_qkv_8ph(
    const u16* __restrict__ A,
    const u16* __restrict__ B0, const u16* __restrict__ B1, const u16* __restrict__ B2,
    const float* __restrict__ c0, const float* __restrict__ c1, const float* __restrict__ c2,
    u16* __restrict__ C, int Mr, int K)
{
  __shared__ u16 lds[2][2][2][16][512];    // [slot][A/B][ks][rowgrp][chunk]
  const int tid  = threadIdx.x;
  const int lane = tid & 63;
  const int wave = tid >> 6;
  const int wm   = wave >> 2;              // 0..1
  const int wn   = wave & 3;               // 0..3

  // XCD-chunked bijective swizzle (960 blocks, 960%8==0): the 12 col-blocks
  // sharing one A row-panel land on the same XCD's L2.
  const int v    = (blockIdx.x & 7) * 120 + (blockIdx.x >> 3);
  const int cb   = v % 12;                 // 0..11: weight + col tile
  const int row0 = (v / 12) * 256;
  const int wsel = cb >> 2;
  const int colL = (cb & 3) * 256;
  const u16*   Bw   = (wsel == 0) ? B0 : (wsel == 1) ? B1 : B2;
  const float* bias = (wsel == 0) ? c0 : (wsel == 1) ? c1 : c2;

  // stage mapping: quad-contiguous global, XOR-permuted octet within quad
  const int srow = lane >> 2;
  const int soct = (((lane & 3) ^ ((lane >> 3) & 3))) << 3;
  int ra0 = row0 + wave * 16 + srow;        if (ra0 >= Mr) ra0 = Mr - 1;
  int ra1 = row0 + 128 + wave * 16 + srow;  if (ra1 >= Mr) ra1 = Mr - 1;
  const u16* pA0 = A + (size_t)ra0 * K + soct;                       // A half0, rowgrp=wave
  const u16* pA1 = A + (size_t)ra1 * K + soct;                       // A half1
  const u16* pB0 = Bw + (size_t)(colL + wave * 16 + srow) * K + soct; // B half0
  const u16* pB1 = pB0 + (size_t)128 * K;                            // B half1

#define STA(S, H, KK, KS) gll16(((H) ? pA1 : pA0) + (KK) + (KS) * 32, \
                                (u16*)&lds[S][0][KS][(H) * 8 + wave][0])
#define STB(S, H, KK, KS) gll16(((H) ? pB1 : pB0) + (KK) + (KS) * 32, \
                                (u16*)&lds[S][1][KS][(H) * 8 + wave][0])

  // fragment read offset within a 512-u16 chunk (conflict-free)
  const int fr  = lane & 15;
  const int fo  = lane >> 4;
  const int lrd = fr * 32 + (((fo ^ ((fr >> 1) & 3))) << 3);
  const int wm8 = wm * 8;                  // A rowgrp base
  const int wn4 = wn * 4;                  // B rowgrp base

#define LDA(S, M, KS) (*(const bf16x8*)&lds[S][0][KS][wm8 + (M)][lrd])
#define LDB(S, N, KS) (*(const bf16x8*)&lds[S][1][KS][wn4 + (N)][lrd])

  f32x4 acc[8][4];
#pragma unroll
  for (int m = 0; m < 8; ++m)
#pragma unroll
    for (int n = 0; n < 4; ++n) acc[m][n] = f32x4{0.f, 0.f, 0.f, 0.f};

  // prologue: tiles 0 (slot0) and 1 (slot1) fully staged, drained
  STA(0, 0, 0, 0);  STA(0, 0, 0, 1);  STA(0, 1, 0, 0);  STA(0, 1, 0, 1);
  STB(0, 0, 0, 0);  STB(0, 0, 0, 1);  STB(0, 1, 0, 0);  STB(0, 1, 0, 1);
  STA(1, 0, 64, 0); STA(1, 0, 64, 1); STA(1, 1, 64, 0); STA(1, 1, 64, 1);
  STB(1, 0, 64, 0); STB(1, 0, 64, 1); STB(1, 1, 64, 0); STB(1, 1, 64, 1);
  asm volatile("s_waitcnt vmcnt(0)" ::: "memory");
  __builtin_amdgcn_s_barrier();

  bf16x8 af[4][2], bf[4][2];
  const int NIT = K >> 7;                  // iterations of 2 K-tiles

#pragma unroll 1
  for (int i = 0; i < NIT; ++i) {
    const int k0  = i * 128;
    const int kc2 = (k0 + 128 <= K - 64) ? k0 + 128 : K - 64;  // tile 2i+2 (clamped)
    const int kc3 = (k0 + 192 <= K - 64) ? k0 + 192 : K - 64;  // tile 2i+3 (clamped)

    // ---- P1: Q00 of slot0 ----
#pragma unroll
    for (int m = 0; m < 4; ++m) { af[m][0] = LDA(0, m, 0); af[m][1] = LDA(0, m, 1); }
#pragma unroll
    for (int n = 0; n < 2; ++n) { bf[n][0] = LDB(0, n, 0); bf[n][1] = LDB(0, n, 1); }
    if (i) { STA(1, 1, k0 + 64, 0); STA(1, 1, k0 + 64, 1); }   // A(2i+1)h1
    asm volatile("s_waitcnt lgkmcnt(8)" ::: "memory");
    __builtin_amdgcn_s_barrier();
    asm volatile("s_waitcnt lgkmcnt(0)" ::: "memory");
    __builtin_amdgcn_s_setprio(1);
#pragma unroll
    for (int m = 0; m < 4; ++m)
#pragma unroll
      for (int n = 0; n < 2; ++n) {
        acc[m][n] = __builtin_amdgcn_mfma_f32_16x16x32_bf16(af[m][0], bf[n][0], acc[m][n], 0, 0, 0);
        acc[m][n] = __builtin_amdgcn_mfma_f32_16x16x32_bf16(af[m][1], bf[n][1], acc[m][n], 0, 0, 0);
      }
    __builtin_amdgcn_s_setprio(0);
    __builtin_amdgcn_s_barrier();

    // ---- P2: Q01 of slot0 ----
#pragma unroll
    for (int n = 2; n < 4; ++n) { bf[n][0] = LDB(0, n, 0); bf[n][1] = LDB(0, n, 1); }
    __builtin_amdgcn_s_barrier();
    asm volatile("s_waitcnt lgkmcnt(0)" ::: "memory");
    __builtin_amdgcn_s_setprio(1);
#pragma unroll
    for (int m = 0; m < 4; ++m)
#pragma unroll
      for (int n = 2; n < 4; ++n) {
        acc[m][n] = __builtin_amdgcn_mfma_f32_16x16x32_bf16(af[m][0], bf[n][0], acc[m][n], 0, 0, 0);
        acc[m][n] = __builtin_amdgcn_mfma_f32_16x16x32_bf16(af[m][1], bf[n][1], acc[m][n], 0, 0, 0);
      }
    __builtin_amdgcn_s_setprio(0);
    __builtin_amdgcn_s_barrier();

    // ---- P3: Q10 of slot0 ----
#pragma unroll
    for (int m = 0; m < 4; ++m) { af[m][0] = LDA(0, 4 + m, 0); af[m][1] = LDA(0, 4 + m, 1); }
    STB(0, 0, kc2, 0); STB(0, 0, kc2, 1);                      // B(2i+2)h0
    __builtin_amdgcn_s_barrier();
    asm volatile("s_waitcnt lgkmcnt(0)" ::: "memory");
    __builtin_amdgcn_s_setprio(1);
#pragma unroll
    for (int m = 0; m < 4; ++m)
#pragma unroll
      for (int n = 0; n < 2; ++n) {
        acc[4 + m][n] = __builtin_amdgcn_mfma_f32_16x16x32_bf16(af[m][0], bf[n][0], acc[4 + m][n], 0, 0, 0);
        acc[4 + m][n] = __builtin_amdgcn_mfma_f32_16x16x32_bf16(af[m][1], bf[n][1], acc[4 + m][n], 0, 0, 0);
      }
    __builtin_amdgcn_s_setprio(0);
    __builtin_amdgcn_s_barrier();

    // ---- P4: Q11 of slot0 (no reads) + W4 ----
    STB(0, 1, kc2, 0); STB(0, 1, kc2, 1);                      // B(2i+2)h1
    STA(0, 0, kc2, 0); STA(0, 0, kc2, 1);                      // A(2i+2)h0
    asm volatile("s_waitcnt vmcnt(6)" ::: "memory");
    __builtin_amdgcn_s_barrier();
    __builtin_amdgcn_s_setprio(1);
#pragma unroll
    for (int m = 0; m < 4; ++m)
#pragma unroll
      for (int n = 2; n < 4; ++n) {
        acc[4 + m][n] = __builtin_amdgcn_mfma_f32_16x16x32_bf16(af[m][0], bf[n][0], acc[4 + m][n], 0, 0, 0);
        acc[4 + m][n] = __builtin_amdgcn_mfma_f32_16x16x32_bf16(af[m][1], bf[n][1], acc[4 + m][n], 0, 0, 0);
      }
    __builtin_amdgcn_s_setprio(0);
    __builtin_amdgcn_s_barrier();

    // ---- P5: Q00 of slot1 ----
#pragma unroll
    for (int m = 0; m < 4; ++m) { af[m][0] = LDA(1, m, 0); af[m][1] = LDA(1, m, 1); }
#pragma unroll
    for (int n = 0; n < 2; ++n) { bf[n][0] = LDB(1, n, 0); bf[n][1] = LDB(1, n, 1); }
    STA(0, 1, kc2, 0); STA(0, 1, kc2, 1);                      // A(2i+2)h1
    asm volatile("s_waitcnt lgkmcnt(8)" ::: "memory");
    __builtin_amdgcn_s_barrier();
    asm volatile("s_waitcnt lgkmcnt(0)" ::: "memory");
    __builtin_amdgcn_s_setprio(1);
#pragma unroll
    for (int m = 0; m < 4; ++m)
#pragma unroll
      for (int n = 0; n < 2; ++n) {
        acc[m][n] = __builtin_amdgcn_mfma_f32_16x16x32_bf16(af[m][0], bf[n][0], acc[m][n], 0, 0, 0);
        acc[m][n] = __builtin_amdgcn_mfma_f32_16x16x32_bf16(af[m][1], bf[n][1], acc[m][n], 0, 0, 0);
      }
    __builtin_amdgcn_s_setprio(0);
    __builtin_amdgcn_s_barrier();

    // ---- P6: Q01 of slot1 ----
#pragma unroll
    for (int n = 2; n < 4; ++n) { bf[n][0] = LDB(1, n, 0); bf[n][1] = LDB(1, n, 1); }
    __builtin_amdgcn_s_barrier();
    asm volatile("s_waitcnt lgkmcnt(0)" ::: "memory");
    __builtin_amdgcn_s_setprio(1);
#pragma unroll
    for (int m = 0; m < 4; ++m)
#pragma unroll
      for (int n = 2; n < 4; ++n) {
        acc[m][n] = __builtin_amdgcn_mfma_f32_16x16x32_bf16(af[m][0], bf[n][0], acc[m][n], 0, 0, 0);
        acc[m][n] = __builtin_amdgcn_mfma_f32_16x16x32_bf16(af[m][1], bf[n][1], acc[m][n], 0, 0, 0);
      }
    __builtin_amdgcn_s_setprio(0);
    __builtin_amdgcn_s_barrier();

    // ---- P7: Q10 of slot1 ----
#pragma unroll
    for (int m = 0; m < 4; ++m) { af[m][0] = LDA(1, 4 + m, 0); af[m][1] = LDA(1, 4 + m, 1); }
    STB(1, 0, kc3, 0); STB(1, 0, kc3, 1);                      // B(2i+3)h0
    __builtin_amdgcn_s_barrier();
    asm volatile("s_waitcnt lgkmcnt(0)" ::: "memory");
    __builtin_amdgcn_s_setprio(1);
#pragma unroll
    for (int m = 0; m < 4; ++m)
#pragma unroll
      for (int n = 0; n < 2; ++n) {
        acc[4 + m][n] = __builtin_amdgcn_mfma_f32_16x16x32_bf16(af[m][0], bf[n][0], acc[4 + m][n], 0, 0, 0);
        acc[4 + m][n] = __builtin_amdgcn_mfma_f32_16x16x32_bf16(af[m][1], bf[n][1], acc[4 + m][n], 0, 0, 0);
      }
    __builtin_amdgcn_s_setprio(0);
    __builtin_amdgcn_s_barrier();

    // ---- P8: Q11 of slot1 (no reads) + W8 ----
    STB(1, 1, kc3, 0); STB(1, 1, kc3, 1);                      // B(2i+3)h1
    STA(1, 0, kc3, 0); STA(1, 0, kc3, 1);                      // A(2i+3)h0
    asm volatile("s_waitcnt vmcnt(6)" ::: "memory");
    __builtin_amdgcn_s_barrier();
    __builtin_amdgcn_s_setprio(1);
#pragma unroll
    for (int m = 0; m < 4; ++m)
#pragma unroll
      for (int n = 2; n < 4; ++n) {
        acc[4 + m][n] = __builtin_amdgcn_mfma_f32_16x16x32_bf16(af[m][0], bf[n][0], acc[4 + m][n], 0, 0, 0);
        acc[4 + m][n] = __builtin_amdgcn_mfma_f32_16x16x32_bf16(af[m][1], bf[n][1], acc[4 + m][n], 0, 0, 0);
      }
    __builtin_amdgcn_s_setprio(0);
    __builtin_amdgcn_s_barrier();
  }
#undef STA
#undef STB
#undef LDA
#undef LDB

  // drain in-flight LDS writes before the workgroup can exit
  asm volatile("s_waitcnt vmcnt(0)" ::: "memory");

  // epilogue: C/D layout col = lane&15, row = (lane>>4)*4 + reg
  const int fc = lane & 15;
  const int rq = (lane >> 4) * 4;
#pragma unroll
  for (int m = 0; m < 8; ++m) {
#pragma unroll
    for (int n = 0; n < 4; ++n) {
      const int cl = wn * 64 + n * 16 + fc;
      const float badd = bias[colL + cl];
      const int gc = cb * 256 + cl;
#pragma unroll
      for (int reg = 0; reg < 4; ++reg) {
        int gr = row0 + wm * 128 + m * 16 + rq + reg;
        if (gr < Mr)
          C[(size_t)gr * 3072 + gc] = f2bf(acc[m][n][reg] + badd);
      }
    }
  }
}

// ---------- ALL projections in ONE launch (segment table, longest-K first) ----------
struct ProjSegs {
  const u16*   A[4];
  const u16*   Bw[4];
  const float* b0[4];
  const float* b1[4];
  int Mr[4], K[4], sl[4], obase[4];
  int blk_end[4];
};
__global__ __launch_bounds__(256) void gemm_proj_all(ProjSegs ps, u16* __restrict__ Cout) {
  int blk = blockIdx.x, seg = 0;
#pragma unroll
  for (int s = 0; s < 3; ++s) if (blk >= ps.blk_end[s]) seg = s + 1;
  const int base  = seg ? ps.blk_end[seg - 1] : 0;
  const int local = blk - base;
  const int row0  = (local >> 3) * 128;
  const int col0  = (local & 7) * 128;
  const int Mr = ps.Mr[seg], K = ps.K[seg], sl = ps.sl[seg], obase = ps.obase[seg];
  const u16* A  = ps.A[seg];
  const u16* Bw = ps.Bw[seg];
  const float* bias0 = ps.b0[seg];
  const float* bias1 = ps.b1[seg];

  __shared__ u16 lA0[128 * 32], lA1[128 * 32];
  __shared__ u16 lB0[128 * 32], lB1[128 * 32];
  const int tid  = threadIdx.x;
  const int lane = tid & 63;
  const int wave = tid >> 6;
  const int wr   = (wave >> 1) * 64;
  const int wc   = (wave & 1) * 64;

  // stage mapping: quad-contiguous global, XOR-permuted octet within quad
  const int srow = lane >> 2;
  const int soct = (((lane & 3) ^ ((lane >> 3) & 3))) << 3;
  int ra0 = row0 + wave * 32 + srow;      if (ra0 >= Mr) ra0 = Mr - 1;
  int ra1 = row0 + wave * 32 + srow + 16; if (ra1 >= Mr) ra1 = Mr - 1;
  const u16* pA0 = A + (size_t)ra0 * K + soct;
  const u16* pA1 = A + (size_t)ra1 * K + soct;
  const u16* pB0 = Bw + (size_t)(col0 + wave * 32 + srow) * K + soct;
  const u16* pB1 = pB0 + (size_t)16 * K;
  u16* dA0a = &lA0[(wave * 32) * 32];      u16* dA1a = &lA0[(wave * 32 + 16) * 32];
  u16* dA0b = &lA1[(wave * 32) * 32];      u16* dA1b = &lA1[(wave * 32 + 16) * 32];
  u16* dB0a = &lB0[(wave * 32) * 32];      u16* dB1a = &lB0[(wave * 32 + 16) * 32];
  u16* dB0b = &lB1[(wave * 32) * 32];      u16* dB1b = &lB1[(wave * 32 + 16) * 32];

  f32x4 acc[4][4];
#pragma unroll
  for (int i = 0; i < 4; ++i)
#pragma unroll
    for (int j = 0; j < 4; ++j) acc[i][j] = f32x4{0.f, 0.f, 0.f, 0.f};

  const int fr  = lane & 15;
  const int fo  = lane >> 4;
  const int lrd = fr * 32 + (((fo ^ ((fr >> 1) & 3))) << 3);
  const int ca  = (wr >> 4) * 512;
  const int cbb = (wc >> 4) * 512;

  for (int k0 = 0; k0 < K; k0 += 64) {
    __syncthreads();
    gll16(pA0 + k0, dA0a);       gll16(pA1 + k0, dA1a);
    gll16(pB0 + k0, dB0a);       gll16(pB1 + k0, dB1a);
    gll16(pA0 + k0 + 32, dA0b);  gll16(pA1 + k0 + 32, dA1b);
    gll16(pB0 + k0 + 32, dB0b);  gll16(pB1 + k0 + 32, dB1b);
    __syncthreads();

    bf16x8 af[4], bfr[4];
#pragma unroll
    for (int j = 0; j < 4; ++j)
      bfr[j] = *(const bf16x8*)&lB0[cbb + j * 512 + lrd];
#pragma unroll
    for (int i = 0; i < 4; ++i)
      af[i] = *(const bf16x8*)&lA0[ca + i * 512 + lrd];
#pragma unroll
    for (int i = 0; i < 4; ++i)
#pragma unroll
      for (int j = 0; j < 4; ++j)
        acc[i][j] = __builtin_amdgcn_mfma_f32_16x16x32_bf16(af[i], bfr[j], acc[i][j], 0, 0, 0);
#pragma unroll
    for (int j = 0; j < 4; ++j)
      bfr[j] = *(const bf16x8*)&lB1[cbb + j * 512 + lrd];
#pragma unroll
    for (int i = 0; i < 4; ++i)
      af[i] = *(const bf16x8*)&lA1[ca + i * 512 + lrd];
#pragma unroll
    for (int i = 0; i < 4; ++i)
#pragma unroll
      for (int j = 0; j < 4; ++j)
        acc[i][j] = __builtin_amdgcn_mfma_f32_16x16x32_bf16(af[i], bfr[j], acc[i][j], 0, 0, 0);
  }

  const int fc = lane & 15;
  const int rq = (lane >> 4) * 4;
#pragma unroll
  for (int i = 0; i < 4; ++i) {
#pragma unroll
    for (int j = 0; j < 4; ++j) {
      const int c = col0 + wc + j * 16 + fc;
      const float badd = bias0[c] + bias1[c];
#pragma unroll
      for (int reg = 0; reg < 4; ++reg) {
        int gr = row0 + wr + i * 16 + rq + reg;
        if (gr < Mr) {
          int bb = gr / sl, ss = gr - bb * sl;
          Cout[(size_t)(bb * RPB + obase + ss) * 1024 + c] = f2bf(acc[i][j][reg] + badd);
        }
      }
    }
  }
}

// ---------- windowed attention + mean over modalities ----------
// ROUTES (IEEE-tie-corrected Cantor): m0:[0,1,2] m1:[0,1,2] m2:[2,3,0] m3:[3,2,0]
__global__ __launch_bounds__(256) void attn_fuse(
    const u16* __restrict__ QKV,   // [RROWS][3072]: Q|K|V
    u16* __restrict__ fused,
    const float* __restrict__ bq, const float* __restrict__ bk, const float* __restrict__ bv,
    const float* __restrict__ temp_ptr)
{
  const int ROUTE[4][3] = {{0,1,2},{0,1,2},{2,3,0},{3,2,0}};
  const int SLm[4]  = {SL0, SL1, SL2, SL3};
  const int OFFS[4] = {0, 2048, 3072, 4572};
  const int tid  = threadIdx.x;
  const int lane = tid & 63;
  const int wave = tid >> 6;
  const int bs   = blockIdx.x * 2 + (wave >> 1);
  const int s    = bs & 2047;
  const int b    = bs >> 11;
  const int h    = (wave & 1) * 8 + (lane >> 3);
  const int sub  = lane & 7;
  const int dbase = h * 64 + sub * 8;
  const float scale = 1.0f / (8.0f * fabsf(temp_ptr[0]));

  float qf[4][8], kf[4][8], vf[4][8];
#pragma unroll
  for (int r = 0; r < 4; ++r) {
    if (s < SLm[r]) {
      const u16* base = QKV + ((size_t)(b * RPB + OFFS[r] + s)) * 3072 + dbase;
      u16x8 q8 = *(const u16x8*)(base);
      u16x8 k8 = *(const u16x8*)(base + 1024);
      u16x8 v8 = *(const u16x8*)(base + 2048);
#pragma unroll
      for (int i = 0; i < 8; ++i) {
        qf[r][i] = bf2f(q8[i]); kf[r][i] = bf2f(k8[i]); vf[r][i] = bf2f(v8[i]);
      }
    } else {
#pragma unroll
      for (int i = 0; i < 8; ++i) {
        qf[r][i] = bq[dbase + i]; kf[r][i] = bk[dbase + i]; vf[r][i] = bv[dbase + i];
      }
    }
  }

  float acc[8];
#pragma unroll
  for (int i = 0; i < 8; ++i) acc[i] = 0.f;

#pragma unroll
  for (int m = 0; m < 4; ++m) {
    float sc[3];
#pragma unroll
    for (int w = 0; w < 3; ++w) {
      const int r = ROUTE[m][w];
      float d = 0.f;
#pragma unroll
      for (int i = 0; i < 8; ++i) d += qf[m][i] * kf[r][i];
      d += __shfl_xor(d, 1, 64);
      d += __shfl_xor(d, 2, 64);
      d += __shfl_xor(d, 4, 64);
      sc[w] = d * scale;
    }
    float mx = fmaxf(sc[0], fmaxf(sc[1], sc[2]));
    float e0 = __expf(sc[0] - mx), e1 = __expf(sc[1] - mx), e2 = __expf(sc[2] - mx);
    float inv = 1.0f / (e0 + e1 + e2);
    float ws[3] = {e0 * inv, e1 * inv, e2 * inv};
#pragma unroll
    for (int w = 0; w < 3; ++w) {
      const int r = ROUTE[m][w];
#pragma unroll
      for (int i = 0; i < 8; ++i) acc[i] += ws[w] * vf[r][i];
    }
  }
  u16x8 o;
#pragma unroll
  for (int i = 0; i < 8; ++i) o[i] = f2bf(acc[i] * 0.25f);
  *(u16x8*)(fused + (size_t)bs * 1024 + dbase) = o;
}

// ---------- host orchestration ----------
extern "C" void kernel_launch(void* const* d_in, const int* in_sizes, int n_in,
                              void* d_out, int out_size, void* d_ws, size_t ws_size,
                              hipStream_t stream) {
  const int B = 4, S = 2048, D = 1024;
  const int SL[4]   = {SL0, SL1, SL2, SL3};
  const int DIM[4]  = {768, 1024, 512, 2048};
  const int OFFS[4] = {0, 2048, 3072, 4572};

  const float* x[4]  = {(const float*)d_in[0], (const float*)d_in[3], (const float*)d_in[6], (const float*)d_in[9]};
  const float* Wm[4] = {(const float*)d_in[1], (const float*)d_in[4], (const float*)d_in[7], (const float*)d_in[10]};
  const float* bm[4] = {(const float*)d_in[2], (const float*)d_in[5], (const float*)d_in[8], (const float*)d_in[11]};
  const float* mod_emb = (const float*)d_in[12];
  const float* Wq = (const float*)d_in[13]; const float* bq = (const float*)d_in[14];
  const float* Wk = (const float*)d_in[15]; const float* bk = (const float*)d_in[16];
  const float* Wv = (const float*)d_in[17]; const float* bv = (const float*)d_in[18];
  const float* Wo = (const float*)d_in[19]; const float* bo = (const float*)d_in[20];
  const float* temp = (const float*)d_in[21];

  const int RROWS = B * RPB;                 // 20336 real rows
  const size_t stackedB = ((size_t)RROWS * D * 2 + 255) / 256 * 256;
  const size_t qkvB     = ((size_t)RROWS * 3 * D * 2 + 255) / 256 * 256;
  const size_t wB       = ((size_t)D * D * 2 + 255) / 256 * 256;
  size_t wmB[4];
  for (int m = 0; m < 4; ++m) wmB[m] = ((size_t)D * DIM[m] * 2 + 255) / 256 * 256;
  const size_t need = stackedB + qkvB + 4 * wB + wmB[0] + wmB[1] + wmB[2] + wmB[3];
  if (ws_size < need) return;                // clean failure, not OOB crash

  char* p = (char*)d_ws;
  u16* stacked = (u16*)p;  p += stackedB;
  char* qkvbase = p;
  u16* qkv     = (u16*)p;  p += qkvB;
  u16* wqb     = (u16*)p;  p += wB;
  u16* wkb     = (u16*)p;  p += wB;
  u16* wvb     = (u16*)p;  p += wB;
  u16* wob     = (u16*)p;  p += wB;
  u16* wmb[4];
  for (int m = 0; m < 4; ++m) { wmb[m] = (u16*)p; p += wmB[m]; }
  u16* fusedb  = stacked;  // stacked dead after QKV GEMM

  // bf16 activations overlaid in the not-yet-live qkv buffer
  u16* xb[4];
  {
    char* q = qkvbase;
    for (int m = 0; m < 4; ++m) {
      xb[m] = (u16*)q;
      q += ((size_t)B * SL[m] * DIM[m] * 2 + 255) / 256 * 256;
    }
  }

  // single fused fp32->bf16 conversion
  {
    CvtSegs cs;
    const float* srcs[NSEG] = {x[0], x[1], x[2], x[3], Wm[0], Wm[1], Wm[2], Wm[3], Wq, Wk, Wv, Wo};
    u16* dsts[NSEG] = {xb[0], xb[1], xb[2], xb[3], wmb[0], wmb[1], wmb[2], wmb[3], wqb, wkb, wvb, wob};
    int ns[NSEG];
    for (int m = 0; m < 4; ++m) ns[m] = B * SL[m] * DIM[m];
    for (int m = 0; m < 4; ++m) ns[4 + m] = D * DIM[m];
    for (int i = 0; i < 4; ++i) ns[8 + i] = D * D;
    int base = 0;
    for (int i = 0; i < NSEG; ++i) {
      cs.src[i] = srcs[i]; cs.dst[i] = dsts[i];
      cs.blk_base[i] = base;
      base += (ns[i] + 1023) / 1024;
      cs.blk_end[i] = base;
    }
    cvt_multi<<<base, 256, 0, stream>>>(cs);
  }

  // ALL projections, one launch, longest-K segment first (video,image,text,audio)
  {
    const int ord[4] = {3, 1, 0, 2};   // by descending K: 2048,1024,768,512
    ProjSegs ps;
    int base = 0;
    for (int i = 0; i < 4; ++i) {
      int m = ord[i];
      int Mr = B * SL[m];
      ps.A[i] = xb[m]; ps.Bw[i] = wmb[m];
      ps.b0[i] = bm[m]; ps.b1[i] = mod_emb + m * D;
      ps.Mr[i] = Mr; ps.K[i] = DIM[m]; ps.sl[i] = SL[m]; ps.obase[i] = OFFS[m];
      base += 8 * ((Mr + 127) / 128);
      ps.blk_end[i] = base;
    }
    gemm_proj_all<<<base, 256, 0, stream>>>(ps, stacked);
  }

  // fused Q|K|V GEMM: [20336 x 3072] = stacked @ [Wq|Wk|Wv]^T
  // 256^2-tile 8-phase deep-pipelined kernel (T2+T3+T4+T5 + XCD swizzle)
  {
    gemm_qkv_8ph<<<12 * ((RROWS + 255) / 256), 512, 0, stream>>>(
        stacked, wqb, wkb, wvb, bq, bk, bv, qkv, RROWS, D);
  }

  // attention over window + mean over modalities -> fused (bf16)
  attn_fuse<<<(B * S) / 2, 256, 0, stream>>>(qkv, fusedb, bq, bk, bv, temp);

  // output GEMM: (B*S) x D, fp32 out
  {
    dim3 grid(8, (B * S) / 128);
    gemm_lds<1><<<grid, 256, 0, stream>>>(fusedb, wob, wob, wob, bo, bo, bo,
                                          d_out, B * S, D, D);
  }
}

// Round 5
// 469.701 us; speedup vs baseline: 1.0015x; 1.0015x over previous
//
#include <hip/hip_runtime.h>

typedef unsigned short u16;
typedef __bf16 bf16x8 __attribute__((ext_vector_type(8)));
typedef u16   u16x8  __attribute__((ext_vector_type(8)));
typedef u16   u16x4  __attribute__((ext_vector_type(4)));
typedef float f32x4  __attribute__((ext_vector_type(4)));

// packed row layout: per batch, modality rows at OFFS[m], total RPB rows/batch
#define RPB 5084
#define SL0 2048
#define SL1 1024
#define SL2 1500
#define SL3 512

// ---------- helpers ----------
__device__ __forceinline__ u16 f2bf(float f) {
  union { float f; unsigned u; } x; x.f = f;
  unsigned u = x.u;
  u += 0x7fffu + ((u >> 16) & 1u);   // RNE
  return (u16)(u >> 16);
}
__device__ __forceinline__ float bf2f(u16 h) {
  union { unsigned u; float f; } x; x.u = ((unsigned)h) << 16;
  return x.f;
}
// async global->LDS, 16B per lane; dest = wave-uniform base + lane*16
__device__ __forceinline__ void gll16(const u16* g, u16* l) {
  __builtin_amdgcn_global_load_lds(
      (const __attribute__((address_space(1))) void*)g,
      (__attribute__((address_space(3))) void*)l, 16, 0, 0);
}

// LDS chunk layout (all GEMMs): each 16-row x 32-k tile is a 1024B chunk.
// Stage lane s fetches global (row s>>2, k-oct (s&3)^((s>>3)&3)) -> lands at
// chunk_base + s*16. Quad s=4q..4q+3 covers one row's 64B contiguously ->
// full coalescing. Fragment read for lane L (row L&15, oct L>>4) sits at
// u16 offset 32*(L&15) + 8*((L>>4)^(((L&15)>>1)&3)); every 8 consecutive
// read lanes hit 8 distinct bank-quads -> ZERO conflicts (verified r2/r3).

// ---------- fused fp32 -> bf16 conversion (flat segments) ----------
#define NSEG 8
struct CvtSegs {
  const float* src[NSEG];
  u16*         dst[NSEG];
  int          blk_end[NSEG];
  int          blk_base[NSEG];
};
__global__ __launch_bounds__(256) void cvt_multi(CvtSegs segs) {
  int blk = blockIdx.x, seg = 0;
#pragma unroll
  for (int s = 0; s < NSEG; ++s) if (blk >= segs.blk_end[s]) seg = s + 1;
  const float* src = segs.src[seg];
  u16* dst = segs.dst[seg];
  int i = (blk - segs.blk_base[seg]) * 1024 + threadIdx.x * 4;
  f32x4 v = *(const f32x4*)(src + i);
  u16x4 o;
  o[0] = f2bf(v[0]); o[1] = f2bf(v[1]); o[2] = f2bf(v[2]); o[3] = f2bf(v[3]);
  *(u16x4*)(dst + i) = o;
}

// ---------- transposing cvt: Wm fp32 [1024][DIM] -> bf16 [DIM][1024] ----------
struct TrSegs { const float* src[4]; u16* dst[4]; int dimc[4]; int blk_end[4]; };
__global__ __launch_bounds__(256) void cvt_transpose(TrSegs ts) {
  __shared__ float t[32][33];
  int blk = blockIdx.x, seg = 0;
#pragma unroll
  for (int s = 0; s < 3; ++s) if (blk >= ts.blk_end[s]) seg = s + 1;
  int base  = seg ? ts.blk_end[seg - 1] : 0;
  int local = blk - base;
  int DIMc  = ts.dimc[seg];
  int tpr   = DIMc >> 5;            // tiles along DIM
  int tr = local / tpr, tc = local - tr * tpr;
  const float* src = ts.src[seg];
  u16* dst = ts.dst[seg];
  int r0 = tr * 32, c0 = tc * 32;
  int cx = threadIdx.x & 31, ry = threadIdx.x >> 5;   // 8 rows/pass, 4 passes
#pragma unroll
  for (int k = 0; k < 4; ++k)
    t[ry + 8 * k][cx] = src[(size_t)(r0 + ry + 8 * k) * DIMc + c0 + cx];
  __syncthreads();
#pragma unroll
  for (int k = 0; k < 4; ++k)
    dst[(size_t)(c0 + ry + 8 * k) * 1024 + r0 + cx] = f2bf(t[cx][ry + 8 * k]);
}

// ---------- bias prep: bqm[m][n] = Wqkv[n]·(bm[m]+emb[m]) + bqkv[n] (fp32) ----------
__global__ __launch_bounds__(256) void bias_prep(
    const float* __restrict__ Wq, const float* __restrict__ Wk, const float* __restrict__ Wv,
    const float* __restrict__ bq, const float* __restrict__ bk, const float* __restrict__ bv,
    const float* __restrict__ bm0, const float* __restrict__ bm1,
    const float* __restrict__ bm2, const float* __restrict__ bm3,
    const float* __restrict__ emb, float* __restrict__ out /*[4][3072]*/)
{
  const int wid  = blockIdx.x * 4 + (threadIdx.x >> 6);   // 0..12287
  const int lane = threadIdx.x & 63;
  const int m = wid / 3072, n = wid - m * 3072;
  const float* wr_ = (n < 1024) ? Wq + (size_t)n * 1024
                   : (n < 2048) ? Wk + (size_t)(n - 1024) * 1024
                                : Wv + (size_t)(n - 2048) * 1024;
  const float  br  = (n < 1024) ? bq[n] : (n < 2048) ? bk[n - 1024] : bv[n - 2048];
  const float* bmp = (m == 0) ? bm0 : (m == 1) ? bm1 : (m == 2) ? bm2 : bm3;
  const float* ep  = emb + (size_t)m * 1024;
  const int k0 = lane * 16;
  float s = 0.f;
#pragma unroll
  for (int i = 0; i < 16; ++i) s += wr_[k0 + i] * (bmp[k0 + i] + ep[k0 + i]);
  s += __shfl_xor(s, 1);  s += __shfl_xor(s, 2);  s += __shfl_xor(s, 4);
  s += __shfl_xor(s, 8);  s += __shfl_xor(s, 16); s += __shfl_xor(s, 32);
  if (lane == 0) out[(size_t)m * 3072 + n] = s + br;
}

// ---------- weight-prep GEMM: Wqkvm[m] = Wqkv(3072x1024) @ Wm^T-view ----------
// A = wq|wk|wv contiguous [3072][1024]; B = wmT[m] [DIM][1024]; C bf16 [3072][DIM].
struct WpSegs { const u16* Bw[4]; u16* Cout[4]; int Nn[4]; int blk_end[4]; };
__global__ __launch_bounds__(256) void gemm_wprep(WpSegs wsg, const u16* __restrict__ A) {
  int blk = blockIdx.x, seg = 0;
#pragma unroll
  for (int s = 0; s < 3; ++s) if (blk >= wsg.blk_end[s]) seg = s + 1;
  const int base  = seg ? wsg.blk_end[seg - 1] : 0;
  const int local = blk - base;
  const int Nn  = wsg.Nn[seg];
  const int ctm = Nn >> 7;
  const int rt  = local / ctm;
  const int row0 = rt * 128, col0 = (local - rt * ctm) * 128;
  const int K = 1024;
  const u16* Bw = wsg.Bw[seg];
  u16* Cout = wsg.Cout[seg];

  __shared__ u16 lA0[128 * 32], lA1[128 * 32];
  __shared__ u16 lB0[128 * 32], lB1[128 * 32];
  const int tid  = threadIdx.x;
  const int lane = tid & 63;
  const int wave = tid >> 6;
  const int wr   = (wave >> 1) * 64;
  const int wc   = (wave & 1) * 64;

  const int srow = lane >> 2;
  const int soct = (((lane & 3) ^ ((lane >> 3) & 3))) << 3;
  const u16* pA0 = A + (size_t)(row0 + wave * 32 + srow) * K + soct;
  const u16* pA1 = pA0 + (size_t)16 * K;
  const u16* pB0 = Bw + (size_t)(col0 + wave * 32 + srow) * K + soct;
  const u16* pB1 = pB0 + (size_t)16 * K;
  u16* dA0a = &lA0[(wave * 32) * 32];      u16* dA1a = &lA0[(wave * 32 + 16) * 32];
  u16* dA0b = &lA1[(wave * 32) * 32];      u16* dA1b = &lA1[(wave * 32 + 16) * 32];
  u16* dB0a = &lB0[(wave * 32) * 32];      u16* dB1a = &lB0[(wave * 32 + 16) * 32];
  u16* dB0b = &lB1[(wave * 32) * 32];      u16* dB1b = &lB1[(wave * 32 + 16) * 32];

  f32x4 acc[4][4];
#pragma unroll
  for (int i = 0; i < 4; ++i)
#pragma unroll
    for (int j = 0; j < 4; ++j) acc[i][j] = f32x4{0.f, 0.f, 0.f, 0.f};

  const int fr  = lane & 15;
  const int fo  = lane >> 4;
  const int lrd = fr * 32 + (((fo ^ ((fr >> 1) & 3))) << 3);
  const int ca  = (wr >> 4) * 512;
  const int cbb = (wc >> 4) * 512;

  for (int k0 = 0; k0 < K; k0 += 64) {
    __syncthreads();
    gll16(pA0 + k0, dA0a);       gll16(pA1 + k0, dA1a);
    gll16(pB0 + k0, dB0a);       gll16(pB1 + k0, dB1a);
    gll16(pA0 + k0 + 32, dA0b);  gll16(pA1 + k0 + 32, dA1b);
    gll16(pB0 + k0 + 32, dB0b);  gll16(pB1 + k0 + 32, dB1b);
    __syncthreads();

    bf16x8 af[4], bfr[4];
#pragma unroll
    for (int j = 0; j < 4; ++j)
      bfr[j] = *(const bf16x8*)&lB0[cbb + j * 512 + lrd];
#pragma unroll
    for (int i = 0; i < 4; ++i)
      af[i] = *(const bf16x8*)&lA0[ca + i * 512 + lrd];
#pragma unroll
    for (int i = 0; i < 4; ++i)
#pragma unroll
      for (int j = 0; j < 4; ++j)
        acc[i][j] = __builtin_amdgcn_mfma_f32_16x16x32_bf16(af[i], bfr[j], acc[i][j], 0, 0, 0);
#pragma unroll
    for (int j = 0; j < 4; ++j)
      bfr[j] = *(const bf16x8*)&lB1[cbb + j * 512 + lrd];
#pragma unroll
    for (int i = 0; i < 4; ++i)
      af[i] = *(const bf16x8*)&lA1[ca + i * 512 + lrd];
#pragma unroll
    for (int i = 0; i < 4; ++i)
#pragma unroll
      for (int j = 0; j < 4; ++j)
        acc[i][j] = __builtin_amdgcn_mfma_f32_16x16x32_bf16(af[i], bfr[j], acc[i][j], 0, 0, 0);
  }

  const int fc = lane & 15;
  const int rq = (lane >> 4) * 4;
#pragma unroll
  for (int i = 0; i < 4; ++i) {
#pragma unroll
    for (int j = 0; j < 4; ++j) {
      const int gc = col0 + wc + j * 16 + fc;
#pragma unroll
      for (int reg = 0; reg < 4; ++reg) {
        int gr = row0 + wr + i * 16 + rq + reg;
        Cout[(size_t)gr * Nn + gc] = f2bf(acc[i][j][reg]);
      }
    }
  }
}

// ---------- m97-style bf16 GEMM (output GEMM) ----------
template<int STORE_F32>
__global__ __launch_bounds__(256) void gemm_lds(
    const u16* __restrict__ A,
    const u16* __restrict__ B0, const u16* __restrict__ B1, const u16* __restrict__ B2,
    const float* __restrict__ c0, const float* __restrict__ c1, const float* __restrict__ c2,
    void* __restrict__ Cout, int Mr, int K, int ldc)
{
  __shared__ u16 lA0[128 * 32], lA1[128 * 32];
  __shared__ u16 lB0[128 * 32], lB1[128 * 32];
  const int tid  = threadIdx.x;
  const int lane = tid & 63;
  const int wave = tid >> 6;
  const int wr   = (wave >> 1) * 64;
  const int wc   = (wave & 1) * 64;
  const int row0 = blockIdx.y * 128;

  const int wsel = blockIdx.x >> 3;
  const int colL = (blockIdx.x & 7) * 128;
  const u16*   Bw   = (wsel == 0) ? B0 : (wsel == 1) ? B1 : B2;
  const float* bias = (wsel == 0) ? c0 : (wsel == 1) ? c1 : c2;

  const int srow = lane >> 2;
  const int soct = (((lane & 3) ^ ((lane >> 3) & 3))) << 3;
  int ra0 = row0 + wave * 32 + srow;      if (ra0 >= Mr) ra0 = Mr - 1;
  int ra1 = row0 + wave * 32 + srow + 16; if (ra1 >= Mr) ra1 = Mr - 1;
  const u16* pA0 = A + (size_t)ra0 * K + soct;
  const u16* pA1 = A + (size_t)ra1 * K + soct;
  const u16* pB0 = Bw + (size_t)(colL + wave * 32 + srow) * K + soct;
  const u16* pB1 = pB0 + (size_t)16 * K;
  u16* dA0a = &lA0[(wave * 32) * 32];      u16* dA1a = &lA0[(wave * 32 + 16) * 32];
  u16* dA0b = &lA1[(wave * 32) * 32];      u16* dA1b = &lA1[(wave * 32 + 16) * 32];
  u16* dB0a = &lB0[(wave * 32) * 32];      u16* dB1a = &lB0[(wave * 32 + 16) * 32];
  u16* dB0b = &lB1[(wave * 32) * 32];      u16* dB1b = &lB1[(wave * 32 + 16) * 32];

  f32x4 acc[4][4];
#pragma unroll
  for (int i = 0; i < 4; ++i)
#pragma unroll
    for (int j = 0; j < 4; ++j) acc[i][j] = f32x4{0.f, 0.f, 0.f, 0.f};

  const int fr  = lane & 15;
  const int fo  = lane >> 4;
  const int lrd = fr * 32 + (((fo ^ ((fr >> 1) & 3))) << 3);
  const int ca  = (wr >> 4) * 512;
  const int cbb = (wc >> 4) * 512;

  for (int k0 = 0; k0 < K; k0 += 64) {
    __syncthreads();
    gll16(pA0 + k0, dA0a);       gll16(pA1 + k0, dA1a);
    gll16(pB0 + k0, dB0a);       gll16(pB1 + k0, dB1a);
    gll16(pA0 + k0 + 32, dA0b);  gll16(pA1 + k0 + 32, dA1b);
    gll16(pB0 + k0 + 32, dB0b);  gll16(pB1 + k0 + 32, dB1b);
    __syncthreads();

    bf16x8 af[4], bfr[4];
#pragma unroll
    for (int j = 0; j < 4; ++j)
      bfr[j] = *(const bf16x8*)&lB0[cbb + j * 512 + lrd];
#pragma unroll
    for (int i = 0; i < 4; ++i)
      af[i] = *(const bf16x8*)&lA0[ca + i * 512 + lrd];
#pragma unroll
    for (int i = 0; i < 4; ++i)
#pragma unroll
      for (int j = 0; j < 4; ++j)
        acc[i][j] = __builtin_amdgcn_mfma_f32_16x16x32_bf16(af[i], bfr[j], acc[i][j], 0, 0, 0);
#pragma unroll
    for (int j = 0; j < 4; ++j)
      bfr[j] = *(const bf16x8*)&lB1[cbb + j * 512 + lrd];
#pragma unroll
    for (int i = 0; i < 4; ++i)
      af[i] = *(const bf16x8*)&lA1[ca + i * 512 + lrd];
#pragma unroll
    for (int i = 0; i < 4; ++i)
#pragma unroll
      for (int j = 0; j < 4; ++j)
        acc[i][j] = __builtin_amdgcn_mfma_f32_16x16x32_bf16(af[i], bfr[j], acc[i][j], 0, 0, 0);
  }

  const int fc = lane & 15;
  const int rq = (lane >> 4) * 4;
#pragma unroll
  for (int i = 0; i < 4; ++i) {
#pragma unroll
    for (int j = 0; j < 4; ++j) {
      const int cl = wc + j * 16 + fc;
      const float badd = bias[colL + cl];
      const int gc = blockIdx.x * 128 + cl;
#pragma unroll
      for (int reg = 0; reg < 4; ++reg) {
        int gr = row0 + wr + i * 16 + rq + reg;
        if (gr < Mr) {
          float v = acc[i][j][reg] + badd;
          if (STORE_F32) ((float*)Cout)[(size_t)gr * ldc + gc] = v;
          else           ((u16*)Cout)[(size_t)gr * ldc + gc] = f2bf(v);
        }
      }
    }
  }
}

// ---------- fused QKV GEMM (direct from X): 256^2, 4-deep ring (r3 structure) ----------
// Per modality segment: C[r][n] = X[r][:] · Wqkvm[n][:] + bqm[n], written to the
// packed qkv rows. 8 waves (2Mx4N), BK=32, vmcnt(8), ONE barrier/K-step,
// conflict-free chunks, coalesced staging (r3-verified best structure).
struct QkvSegs {
  const u16*   A[4];
  const u16*   Bw[4];
  const float* bias[4];
  int Mr[4], K[4], sl[4], obase[4], blk_end[4];
};
__global__ __launch_bounds__(512, 2) void gemm_qkv_seg(QkvSegs qs, u16* __restrict__ C) {
  __shared__ u16 lds[4][2][8192];          // [slot][A/B][16 chunks x 512]
  int blk = blockIdx.x, seg = 0;
#pragma unroll
  for (int s = 0; s < 3; ++s) if (blk >= qs.blk_end[s]) seg = s + 1;
  const int base  = seg ? qs.blk_end[seg - 1] : 0;
  const int local = blk - base;
  const int cbt   = local % 12;            // col tile (12 x 256 = 3072)
  const int row0  = (local / 12) * 256;
  const int colL  = cbt * 256;
  const int Mr = qs.Mr[seg], K = qs.K[seg], sl = qs.sl[seg], obase = qs.obase[seg];
  const u16* A  = qs.A[seg];
  const u16* Bw = qs.Bw[seg];
  const float* bias = qs.bias[seg];

  const int tid  = threadIdx.x;
  const int lane = tid & 63;
  const int wave = tid >> 6;
  const int wm   = wave >> 2;              // 0..1
  const int wn   = wave & 3;               // 0..3

  const int srow = lane >> 2;
  const int soct = (((lane & 3) ^ ((lane >> 3) & 3))) << 3;
  int ra0 = row0 + wave * 16 + srow;        if (ra0 >= Mr) ra0 = Mr - 1;
  int ra1 = row0 + 128 + wave * 16 + srow;  if (ra1 >= Mr) ra1 = Mr - 1;
  const u16* pA0 = A + (size_t)ra0 * K + soct;
  const u16* pA1 = A + (size_t)ra1 * K + soct;
  const u16* pB0 = Bw + (size_t)(colL + wave * 16 + srow) * K + soct;
  const u16* pB1 = pB0 + (size_t)128 * K;
  const int NS = K >> 5;                    // K-steps of 32 (>=16 for all segments)

#define QSTAGE(slot, k0) do {                                   \
    gll16(pA0 + (k0), (u16*)&lds[slot][0][wave * 512]);         \
    gll16(pA1 + (k0), (u16*)&lds[slot][0][4096 + wave * 512]);  \
    gll16(pB0 + (k0), (u16*)&lds[slot][1][wave * 512]);         \
    gll16(pB1 + (k0), (u16*)&lds[slot][1][4096 + wave * 512]);  \
  } while (0)

  f32x4 acc[8][4];
#pragma unroll
  for (int m = 0; m < 8; ++m)
#pragma unroll
    for (int n = 0; n < 4; ++n) acc[m][n] = f32x4{0.f, 0.f, 0.f, 0.f};

  // prologue: 3 tiles in flight (12 VMEM items/wave)
  QSTAGE(0, 0);
  QSTAGE(1, 32);
  QSTAGE(2, 64);

  const int fr  = lane & 15;
  const int fo  = lane >> 4;
  const int lrd = fr * 32 + (((fo ^ ((fr >> 1) & 3))) << 3);
  const int cam = wm * 8 * 512;
  const int cbn = wn * 4 * 512;

#pragma unroll 4
  for (int s = 0; s < NS; ++s) {
    asm volatile("s_waitcnt vmcnt(8)" ::: "memory");
    __builtin_amdgcn_s_barrier();
    asm volatile("" ::: "memory");         // no loads/stages above the barrier

    const u16* Ab = &lds[s & 3][0][0];
    const u16* Bb = &lds[s & 3][1][0];
    bf16x8 af[8], bf[4];
#pragma unroll
    for (int n = 0; n < 4; ++n)
      bf[n] = *(const bf16x8*)&Bb[cbn + n * 512 + lrd];
#pragma unroll
    for (int m = 0; m < 8; ++m)
      af[m] = *(const bf16x8*)&Ab[cam + m * 512 + lrd];

    const int s3 = s + 3;
    const int k3 = (s3 < NS ? s3 : NS - 1) << 5;
    QSTAGE(s3 & 3, k3);

#pragma unroll
    for (int m = 0; m < 8; ++m)
#pragma unroll
      for (int n = 0; n < 4; ++n)
        acc[m][n] = __builtin_amdgcn_mfma_f32_16x16x32_bf16(af[m], bf[n], acc[m][n], 0, 0, 0);
  }
#undef QSTAGE

  asm volatile("s_waitcnt vmcnt(0)" ::: "memory");

  // epilogue: packed-row write; C/D layout col = lane&15, row = (lane>>4)*4 + reg
  const int fc = lane & 15;
  const int rq = (lane >> 4) * 4;
#pragma unroll
  for (int m = 0; m < 8; ++m) {
#pragma unroll
    for (int n = 0; n < 4; ++n) {
      const int cl = wn * 64 + n * 16 + fc;
      const float badd = bias[colL + cl];
      const int gc = colL + cl;
#pragma unroll
      for (int reg = 0; reg < 4; ++reg) {
        int gr = row0 + wm * 128 + m * 16 + rq + reg;
        if (gr < Mr) {
          int bb = gr / sl, ss = gr - bb * sl;
          C[(size_t)(bb * RPB + obase + ss) * 3072 + gc] = f2bf(acc[m][n][reg] + badd);
        }
      }
    }
  }
}

// ---------- windowed attention + mean over modalities ----------
// ROUTES (IEEE-tie-corrected Cantor): m0:[0,1,2] m1:[0,1,2] m2:[2,3,0] m3:[3,2,0]
__global__ __launch_bounds__(256) void attn_fuse(
    const u16* __restrict__ QKV,   // [RROWS][3072]: Q|K|V
    u16* __restrict__ fused,
    const float* __restrict__ bq, const float* __restrict__ bk, const float* __restrict__ bv,
    const float* __restrict__ temp_ptr)
{
  const int ROUTE[4][3] = {{0,1,2},{0,1,2},{2,3,0},{3,2,0}};
  const int SLm[4]  = {SL0, SL1, SL2, SL3};
  const int OFFS[4] = {0, 2048, 3072, 4572};
  const int tid  = threadIdx.x;
  const int lane = tid & 63;
  const int wave = tid >> 6;
  const int bs   = blockIdx.x * 2 + (wave >> 1);
  const int s    = bs & 2047;
  const int b    = bs >> 11;
  const int h    = (wave & 1) * 8 + (lane >> 3);
  const int sub  = lane & 7;
  const int dbase = h * 64 + sub * 8;
  const float scale = 1.0f / (8.0f * fabsf(temp_ptr[0]));

  float qf[4][8], kf[4][8], vf[4][8];
#pragma unroll
  for (int r = 0; r < 4; ++r) {
    if (s < SLm[r]) {
      const u16* base = QKV + ((size_t)(b * RPB + OFFS[r] + s)) * 3072 + dbase;
      u16x8 q8 = *(const u16x8*)(base);
      u16x8 k8 = *(const u16x8*)(base + 1024);
      u16x8 v8 = *(const u16x8*)(base + 2048);
#pragma unroll
      for (int i = 0; i < 8; ++i) {
        qf[r][i] = bf2f(q8[i]); kf[r][i] = bf2f(k8[i]); vf[r][i] = bf2f(v8[i]);
      }
    } else {
#pragma unroll
      for (int i = 0; i < 8; ++i) {
        qf[r][i] = bq[dbase + i]; kf[r][i] = bk[dbase + i]; vf[r][i] = bv[dbase + i];
      }
    }
  }

  float acc[8];
#pragma unroll
  for (int i = 0; i < 8; ++i) acc[i] = 0.f;

#pragma unroll
  for (int m = 0; m < 4; ++m) {
    float sc[3];
#pragma unroll
    for (int w = 0; w < 3; ++w) {
      const int r = ROUTE[m][w];
      float d = 0.f;
#pragma unroll
      for (int i = 0; i < 8; ++i) d += qf[m][i] * kf[r][i];
      d += __shfl_xor(d, 1, 64);
      d += __shfl_xor(d, 2, 64);
      d += __shfl_xor(d, 4, 64);
      sc[w] = d * scale;
    }
    float mx = fmaxf(sc[0], fmaxf(sc[1], sc[2]));
    float e0 = __expf(sc[0] - mx), e1 = __expf(sc[1] - mx), e2 = __expf(sc[2] - mx);
    float inv = 1.0f / (e0 + e1 + e2);
    float ws[3] = {e0 * inv, e1 * inv, e2 * inv};
#pragma unroll
    for (int w = 0; w < 3; ++w) {
      const int r = ROUTE[m][w];
#pragma unroll
      for (int i = 0; i < 8; ++i) acc[i] += ws[w] * vf[r][i];
    }
  }
  u16x8 o;
#pragma unroll
  for (int i = 0; i < 8; ++i) o[i] = f2bf(acc[i] * 0.25f);
  *(u16x8*)(fused + (size_t)bs * 1024 + dbase) = o;
}

// ---------- host orchestration ----------
extern "C" void kernel_launch(void* const* d_in, const int* in_sizes, int n_in,
                              void* d_out, int out_size, void* d_ws, size_t ws_size,
                              hipStream_t stream) {
  const int B = 4, S = 2048, D = 1024;
  const int SL[4]   = {SL0, SL1, SL2, SL3};
  const int DIM[4]  = {768, 1024, 512, 2048};
  const int OFFS[4] = {0, 2048, 3072, 4572};

  const float* x[4]  = {(const float*)d_in[0], (const float*)d_in[3], (const float*)d_in[6], (const float*)d_in[9]};
  const float* Wm[4] = {(const float*)d_in[1], (const float*)d_in[4], (const float*)d_in[7], (const float*)d_in[10]};
  const float* bm[4] = {(const float*)d_in[2], (const float*)d_in[5], (const float*)d_in[8], (const float*)d_in[11]};
  const float* mod_emb = (const float*)d_in[12];
  const float* Wq = (const float*)d_in[13]; const float* bq = (const float*)d_in[14];
  const float* Wk = (const float*)d_in[15]; const float* bk = (const float*)d_in[16];
  const float* Wv = (const float*)d_in[17]; const float* bv = (const float*)d_in[18];
  const float* Wo = (const float*)d_in[19]; const float* bo = (const float*)d_in[20];
  const float* temp = (const float*)d_in[21];

  const int RROWS = B * RPB;                 // 20336 real rows
  const size_t qkvB   = ((size_t)RROWS * 3 * D * 2 + 255) / 256 * 256;
  size_t xbB[4], wmTB[4], wqkvmB[4];
  size_t xbTot = 0, wmTTot = 0, wqkvmTot = 0;
  for (int m = 0; m < 4; ++m) {
    xbB[m]    = ((size_t)B * SL[m] * DIM[m] * 2 + 255) / 256 * 256;  xbTot    += xbB[m];
    wmTB[m]   = ((size_t)DIM[m] * D * 2 + 255) / 256 * 256;          wmTTot   += wmTB[m];
    wqkvmB[m] = ((size_t)3 * D * DIM[m] * 2 + 255) / 256 * 256;      wqkvmTot += wqkvmB[m];
  }
  const size_t wB   = (size_t)D * D * 2;     // exactly 2 MB, keeps wq|wk|wv contiguous
  const size_t bqmB = ((size_t)4 * 3 * D * 4 + 255) / 256 * 256;
  const size_t need = qkvB + xbTot + wmTTot + 3 * wB + wB + wqkvmTot + bqmB;
  if (ws_size < need) return;                // clean failure, not OOB crash

  char* p = (char*)d_ws;
  u16* qkv = (u16*)p;  p += qkvB;
  u16* xb[4];
  char* xbBase = p;
  for (int m = 0; m < 4; ++m) { xb[m] = (u16*)p; p += xbB[m]; }
  u16* wmT[4];
  for (int m = 0; m < 4; ++m) { wmT[m] = (u16*)p; p += wmTB[m]; }
  u16* wqb = (u16*)p;  p += wB;              // wq|wk|wv contiguous = [3072][1024]
  u16* wkb = (u16*)p;  p += wB;
  u16* wvb = (u16*)p;  p += wB;
  u16* wob = (u16*)p;  p += wB;
  u16* wqkvm[4];
  for (int m = 0; m < 4; ++m) { wqkvm[m] = (u16*)p; p += wqkvmB[m]; }
  float* bqm = (float*)p;  p += bqmB;
  u16* fusedb = (u16*)xbBase;                // xb dead after QKV GEMM

  // flat fp32->bf16 conversion: 4 activations + Wq,Wk,Wv,Wo
  {
    CvtSegs cs;
    const float* srcs[NSEG] = {x[0], x[1], x[2], x[3], Wq, Wk, Wv, Wo};
    u16* dsts[NSEG] = {xb[0], xb[1], xb[2], xb[3], wqb, wkb, wvb, wob};
    int ns[NSEG];
    for (int m = 0; m < 4; ++m) ns[m] = B * SL[m] * DIM[m];
    for (int i = 0; i < 4; ++i) ns[4 + i] = D * D;
    int base = 0;
    for (int i = 0; i < NSEG; ++i) {
      cs.src[i] = srcs[i]; cs.dst[i] = dsts[i];
      cs.blk_base[i] = base;
      base += (ns[i] + 1023) / 1024;
      cs.blk_end[i] = base;
    }
    cvt_multi<<<base, 256, 0, stream>>>(cs);
  }

  // transposed conversion of Wm: fp32 [1024][DIM] -> bf16 [DIM][1024]
  {
    TrSegs ts;
    int base = 0;
    for (int m = 0; m < 4; ++m) {
      ts.src[m] = Wm[m]; ts.dst[m] = wmT[m]; ts.dimc[m] = DIM[m];
      base += (D / 32) * (DIM[m] / 32);
      ts.blk_end[m] = base;
    }
    cvt_transpose<<<base, 256, 0, stream>>>(ts);
  }

  // fused bias: bqm[m][n] = Wqkv[n]·(bm[m]+emb[m]) + bqkv[n]  (fp32 inputs)
  bias_prep<<<3072, 256, 0, stream>>>(Wq, Wk, Wv, bq, bk, bv,
                                      bm[0], bm[1], bm[2], bm[3], mod_emb, bqm);

  // weight prep: Wqkvm[m] = [Wq;Wk;Wv] @ Wm[m]  -> bf16 [3072][DIM[m]]
  {
    const int ord[4] = {3, 1, 0, 2};   // by descending N: 2048,1024,768,512
    WpSegs wsg;
    int base = 0;
    for (int i = 0; i < 4; ++i) {
      int m = ord[i];
      wsg.Bw[i] = wmT[m]; wsg.Cout[i] = wqkvm[m]; wsg.Nn[i] = DIM[m];
      base += (3 * D / 128) * (DIM[m] / 128);
      wsg.blk_end[i] = base;
    }
    gemm_wprep<<<base, 256, 0, stream>>>(wsg, wqb);
  }

  // fused QKV GEMM: qkv rows = X @ Wqkvm^T + bqm (per modality, packed rows)
  {
    const int ord[4] = {3, 1, 0, 2};   // by descending K: 2048,1024,768,512
    QkvSegs qsg;
    int base = 0;
    for (int i = 0; i < 4; ++i) {
      int m = ord[i];
      int Mr = B * SL[m];
      qsg.A[i] = xb[m]; qsg.Bw[i] = wqkvm[m]; qsg.bias[i] = bqm + m * 3072;
      qsg.Mr[i] = Mr; qsg.K[i] = DIM[m]; qsg.sl[i] = SL[m]; qsg.obase[i] = OFFS[m];
      base += 12 * ((Mr + 255) / 256);
      qsg.blk_end[i] = base;
    }
    gemm_qkv_seg<<<base, 512, 0, stream>>>(qsg, qkv);
  }

  // attention over window + mean over modalities -> fused (bf16, overlays xb)
  attn_fuse<<<(B * S) / 2, 256, 0, stream>>>(qkv, fusedb, bq, bk, bv, temp);

  // output GEMM: (B*S) x D, fp32 out
  {
    dim3 grid(8, (B * S) / 128);
    gemm_lds<1><<<grid, 256, 0, stream>>>(fusedb, wob, wob, wob, bo, bo, bo,
                                          d_out, B * S, D, D);
  }
}

// Round 6
// 419.495 us; speedup vs baseline: 1.1214x; 1.1197x over previous
//
#include <hip/hip_runtime.h>

typedef unsigned short u16;
typedef __bf16 bf16x8 __attribute__((ext_vector_type(8)));
typedef u16   u16x8  __attribute__((ext_vector_type(8)));
typedef u16   u16x4  __attribute__((ext_vector_type(4)));
typedef float f32x4  __attribute__((ext_vector_type(4)));

// packed row layout: per batch, modality rows at OFFS[m], total RPB rows/batch
#define RPB 5084
#define SL0 2048
#define SL1 1024
#define SL2 1500
#define SL3 512

// ---------- helpers ----------
__device__ __forceinline__ u16 f2bf(float f) {
  union { float f; unsigned u; } x; x.f = f;
  unsigned u = x.u;
  u += 0x7fffu + ((u >> 16) & 1u);   // RNE
  return (u16)(u >> 16);
}
__device__ __forceinline__ float bf2f(u16 h) {
  union { unsigned u; float f; } x; x.u = ((unsigned)h) << 16;
  return x.f;
}
// async global->LDS, 16B per lane; dest = wave-uniform base + lane*16
__device__ __forceinline__ void gll16(const u16* g, u16* l) {
  __builtin_amdgcn_global_load_lds(
      (const __attribute__((address_space(1))) void*)g,
      (__attribute__((address_space(3))) void*)l, 16, 0, 0);
}

// LDS chunk layout (all GEMMs): each 16-row x 32-k tile is a 1024B chunk.
// Stage lane s fetches global (row s>>2, k-oct (s&3)^((s>>3)&3)) -> lands at
// chunk_base + s*16. Quad s=4q..4q+3 covers one row's 64B contiguously ->
// full coalescing. Fragment read for lane L (row L&15, oct L>>4) sits at
// u16 offset 32*(L&15) + 8*((L>>4)^(((L&15)>>1)&3)); every 8 consecutive
// read lanes hit 8 distinct bank-quads -> ZERO conflicts (verified r2/r3).

// ---------- merged prep: flat cvt (8 segs) | Wm transpose (4 segs) | bias ----------
struct PrepAll {
  const float* csrc[8]; u16* cdst[8]; int cend[8]; int cbase[8];
  const float* tsrc[4]; u16* tdst[4]; int tdim[4]; int tend[4];
  const float *Wq, *Wk, *Wv, *bq, *bk, *bv, *bm0, *bm1, *bm2, *bm3, *emb;
  float* bout;
  int cvtN, trN;
};
__global__ __launch_bounds__(256) void prep_all(PrepAll pa) {
  __shared__ float t[32][33];
  int blk = blockIdx.x;
  if (blk < pa.cvtN) {
    // flat fp32 -> bf16
    int seg = 0;
#pragma unroll
    for (int s = 0; s < 8; ++s) if (blk >= pa.cend[s]) seg = s + 1;
    const float* src = pa.csrc[seg];
    u16* dst = pa.cdst[seg];
    int i = (blk - pa.cbase[seg]) * 1024 + threadIdx.x * 4;
    f32x4 v = *(const f32x4*)(src + i);
    u16x4 o;
    o[0] = f2bf(v[0]); o[1] = f2bf(v[1]); o[2] = f2bf(v[2]); o[3] = f2bf(v[3]);
    *(u16x4*)(dst + i) = o;
    return;
  }
  blk -= pa.cvtN;
  if (blk < pa.trN) {
    // Wm fp32 [1024][DIM] -> bf16 [DIM][1024]
    int seg = 0;
#pragma unroll
    for (int s = 0; s < 3; ++s) if (blk >= pa.tend[s]) seg = s + 1;
    int base  = seg ? pa.tend[seg - 1] : 0;
    int local = blk - base;
    int DIMc  = pa.tdim[seg];
    int tpr   = DIMc >> 5;
    int tr = local / tpr, tc = local - tr * tpr;
    const float* src = pa.tsrc[seg];
    u16* dst = pa.tdst[seg];
    int r0 = tr * 32, c0 = tc * 32;
    int cx = threadIdx.x & 31, ry = threadIdx.x >> 5;
#pragma unroll
    for (int k = 0; k < 4; ++k)
      t[ry + 8 * k][cx] = src[(size_t)(r0 + ry + 8 * k) * DIMc + c0 + cx];
    __syncthreads();
#pragma unroll
    for (int k = 0; k < 4; ++k)
      dst[(size_t)(c0 + ry + 8 * k) * 1024 + r0 + cx] = f2bf(t[cx][ry + 8 * k]);
    return;
  }
  blk -= pa.trN;
  // bias: bout[m][n] = Wqkv[n]·(bm[m]+emb[m]) + bqkv[n]
  const int wid  = blk * 4 + (threadIdx.x >> 6);   // 0..12287
  const int lane = threadIdx.x & 63;
  const int m = wid / 3072, n = wid - m * 3072;
  const float* wr_ = (n < 1024) ? pa.Wq + (size_t)n * 1024
                   : (n < 2048) ? pa.Wk + (size_t)(n - 1024) * 1024
                                : pa.Wv + (size_t)(n - 2048) * 1024;
  const float  br  = (n < 1024) ? pa.bq[n] : (n < 2048) ? pa.bk[n - 1024] : pa.bv[n - 2048];
  const float* bmp = (m == 0) ? pa.bm0 : (m == 1) ? pa.bm1 : (m == 2) ? pa.bm2 : pa.bm3;
  const float* ep  = pa.emb + (size_t)m * 1024;
  const int k0 = lane * 16;
  float s = 0.f;
#pragma unroll
  for (int i = 0; i < 16; ++i) s += wr_[k0 + i] * (bmp[k0 + i] + ep[k0 + i]);
  s += __shfl_xor(s, 1);  s += __shfl_xor(s, 2);  s += __shfl_xor(s, 4);
  s += __shfl_xor(s, 8);  s += __shfl_xor(s, 16); s += __shfl_xor(s, 32);
  if (lane == 0) pa.bout[(size_t)m * 3072 + n] = s + br;
}

// ---------- weight-prep GEMM: Wqkvm[m] = Wqkv(3072x1024) @ Wm^T-view ----------
struct WpSegs { const u16* Bw[4]; u16* Cout[4]; int Nn[4]; int blk_end[4]; };
__global__ __launch_bounds__(256) void gemm_wprep(WpSegs wsg, const u16* __restrict__ A) {
  int blk = blockIdx.x, seg = 0;
#pragma unroll
  for (int s = 0; s < 3; ++s) if (blk >= wsg.blk_end[s]) seg = s + 1;
  const int base  = seg ? wsg.blk_end[seg - 1] : 0;
  const int local = blk - base;
  const int Nn  = wsg.Nn[seg];
  const int ctm = Nn >> 7;
  const int rt  = local / ctm;
  const int row0 = rt * 128, col0 = (local - rt * ctm) * 128;
  const int K = 1024;
  const u16* Bw = wsg.Bw[seg];
  u16* Cout = wsg.Cout[seg];

  __shared__ u16 lA0[128 * 32], lA1[128 * 32];
  __shared__ u16 lB0[128 * 32], lB1[128 * 32];
  const int tid  = threadIdx.x;
  const int lane = tid & 63;
  const int wave = tid >> 6;
  const int wr   = (wave >> 1) * 64;
  const int wc   = (wave & 1) * 64;

  const int srow = lane >> 2;
  const int soct = (((lane & 3) ^ ((lane >> 3) & 3))) << 3;
  const u16* pA0 = A + (size_t)(row0 + wave * 32 + srow) * K + soct;
  const u16* pA1 = pA0 + (size_t)16 * K;
  const u16* pB0 = Bw + (size_t)(col0 + wave * 32 + srow) * K + soct;
  const u16* pB1 = pB0 + (size_t)16 * K;
  u16* dA0a = &lA0[(wave * 32) * 32];      u16* dA1a = &lA0[(wave * 32 + 16) * 32];
  u16* dA0b = &lA1[(wave * 32) * 32];      u16* dA1b = &lA1[(wave * 32 + 16) * 32];
  u16* dB0a = &lB0[(wave * 32) * 32];      u16* dB1a = &lB0[(wave * 32 + 16) * 32];
  u16* dB0b = &lB1[(wave * 32) * 32];      u16* dB1b = &lB1[(wave * 32 + 16) * 32];

  f32x4 acc[4][4];
#pragma unroll
  for (int i = 0; i < 4; ++i)
#pragma unroll
    for (int j = 0; j < 4; ++j) acc[i][j] = f32x4{0.f, 0.f, 0.f, 0.f};

  const int fr  = lane & 15;
  const int fo  = lane >> 4;
  const int lrd = fr * 32 + (((fo ^ ((fr >> 1) & 3))) << 3);
  const int ca  = (wr >> 4) * 512;
  const int cbb = (wc >> 4) * 512;

  for (int k0 = 0; k0 < K; k0 += 64) {
    __syncthreads();
    gll16(pA0 + k0, dA0a);       gll16(pA1 + k0, dA1a);
    gll16(pB0 + k0, dB0a);       gll16(pB1 + k0, dB1a);
    gll16(pA0 + k0 + 32, dA0b);  gll16(pA1 + k0 + 32, dA1b);
    gll16(pB0 + k0 + 32, dB0b);  gll16(pB1 + k0 + 32, dB1b);
    __syncthreads();

    bf16x8 af[4], bfr[4];
#pragma unroll
    for (int j = 0; j < 4; ++j)
      bfr[j] = *(const bf16x8*)&lB0[cbb + j * 512 + lrd];
#pragma unroll
    for (int i = 0; i < 4; ++i)
      af[i] = *(const bf16x8*)&lA0[ca + i * 512 + lrd];
#pragma unroll
    for (int i = 0; i < 4; ++i)
#pragma unroll
      for (int j = 0; j < 4; ++j)
        acc[i][j] = __builtin_amdgcn_mfma_f32_16x16x32_bf16(af[i], bfr[j], acc[i][j], 0, 0, 0);
#pragma unroll
    for (int j = 0; j < 4; ++j)
      bfr[j] = *(const bf16x8*)&lB1[cbb + j * 512 + lrd];
#pragma unroll
    for (int i = 0; i < 4; ++i)
      af[i] = *(const bf16x8*)&lA1[ca + i * 512 + lrd];
#pragma unroll
    for (int i = 0; i < 4; ++i)
#pragma unroll
      for (int j = 0; j < 4; ++j)
        acc[i][j] = __builtin_amdgcn_mfma_f32_16x16x32_bf16(af[i], bfr[j], acc[i][j], 0, 0, 0);
  }

  const int fc = lane & 15;
  const int rq = (lane >> 4) * 4;
#pragma unroll
  for (int i = 0; i < 4; ++i) {
#pragma unroll
    for (int j = 0; j < 4; ++j) {
      const int gc = col0 + wc + j * 16 + fc;
#pragma unroll
      for (int reg = 0; reg < 4; ++reg) {
        int gr = row0 + wr + i * 16 + rq + reg;
        Cout[(size_t)gr * Nn + gc] = f2bf(acc[i][j][reg]);
      }
    }
  }
}

// ---------- m97-style bf16 GEMM (output GEMM) ----------
template<int STORE_F32>
__global__ __launch_bounds__(256) void gemm_lds(
    const u16* __restrict__ A,
    const u16* __restrict__ B0, const u16* __restrict__ B1, const u16* __restrict__ B2,
    const float* __restrict__ c0, const float* __restrict__ c1, const float* __restrict__ c2,
    void* __restrict__ Cout, int Mr, int K, int ldc)
{
  __shared__ u16 lA0[128 * 32], lA1[128 * 32];
  __shared__ u16 lB0[128 * 32], lB1[128 * 32];
  const int tid  = threadIdx.x;
  const int lane = tid & 63;
  const int wave = tid >> 6;
  const int wr   = (wave >> 1) * 64;
  const int wc   = (wave & 1) * 64;
  const int row0 = blockIdx.y * 128;

  const int wsel = blockIdx.x >> 3;
  const int colL = (blockIdx.x & 7) * 128;
  const u16*   Bw   = (wsel == 0) ? B0 : (wsel == 1) ? B1 : B2;
  const float* bias = (wsel == 0) ? c0 : (wsel == 1) ? c1 : c2;

  const int srow = lane >> 2;
  const int soct = (((lane & 3) ^ ((lane >> 3) & 3))) << 3;
  int ra0 = row0 + wave * 32 + srow;      if (ra0 >= Mr) ra0 = Mr - 1;
  int ra1 = row0 + wave * 32 + srow + 16; if (ra1 >= Mr) ra1 = Mr - 1;
  const u16* pA0 = A + (size_t)ra0 * K + soct;
  const u16* pA1 = A + (size_t)ra1 * K + soct;
  const u16* pB0 = Bw + (size_t)(colL + wave * 32 + srow) * K + soct;
  const u16* pB1 = pB0 + (size_t)16 * K;
  u16* dA0a = &lA0[(wave * 32) * 32];      u16* dA1a = &lA0[(wave * 32 + 16) * 32];
  u16* dA0b = &lA1[(wave * 32) * 32];      u16* dA1b = &lA1[(wave * 32 + 16) * 32];
  u16* dB0a = &lB0[(wave * 32) * 32];      u16* dB1a = &lB0[(wave * 32 + 16) * 32];
  u16* dB0b = &lB1[(wave * 32) * 32];      u16* dB1b = &lB1[(wave * 32 + 16) * 32];

  f32x4 acc[4][4];
#pragma unroll
  for (int i = 0; i < 4; ++i)
#pragma unroll
    for (int j = 0; j < 4; ++j) acc[i][j] = f32x4{0.f, 0.f, 0.f, 0.f};

  const int fr  = lane & 15;
  const int fo  = lane >> 4;
  const int lrd = fr * 32 + (((fo ^ ((fr >> 1) & 3))) << 3);
  const int ca  = (wr >> 4) * 512;
  const int cbb = (wc >> 4) * 512;

  for (int k0 = 0; k0 < K; k0 += 64) {
    __syncthreads();
    gll16(pA0 + k0, dA0a);       gll16(pA1 + k0, dA1a);
    gll16(pB0 + k0, dB0a);       gll16(pB1 + k0, dB1a);
    gll16(pA0 + k0 + 32, dA0b);  gll16(pA1 + k0 + 32, dA1b);
    gll16(pB0 + k0 + 32, dB0b);  gll16(pB1 + k0 + 32, dB1b);
    __syncthreads();

    bf16x8 af[4], bfr[4];
#pragma unroll
    for (int j = 0; j < 4; ++j)
      bfr[j] = *(const bf16x8*)&lB0[cbb + j * 512 + lrd];
#pragma unroll
    for (int i = 0; i < 4; ++i)
      af[i] = *(const bf16x8*)&lA0[ca + i * 512 + lrd];
#pragma unroll
    for (int i = 0; i < 4; ++i)
#pragma unroll
      for (int j = 0; j < 4; ++j)
        acc[i][j] = __builtin_amdgcn_mfma_f32_16x16x32_bf16(af[i], bfr[j], acc[i][j], 0, 0, 0);
#pragma unroll
    for (int j = 0; j < 4; ++j)
      bfr[j] = *(const bf16x8*)&lB1[cbb + j * 512 + lrd];
#pragma unroll
    for (int i = 0; i < 4; ++i)
      af[i] = *(const bf16x8*)&lA1[ca + i * 512 + lrd];
#pragma unroll
    for (int i = 0; i < 4; ++i)
#pragma unroll
      for (int j = 0; j < 4; ++j)
        acc[i][j] = __builtin_amdgcn_mfma_f32_16x16x32_bf16(af[i], bfr[j], acc[i][j], 0, 0, 0);
  }

  const int fc = lane & 15;
  const int rq = (lane >> 4) * 4;
#pragma unroll
  for (int i = 0; i < 4; ++i) {
#pragma unroll
    for (int j = 0; j < 4; ++j) {
      const int cl = wc + j * 16 + fc;
      const float badd = bias[colL + cl];
      const int gc = blockIdx.x * 128 + cl;
#pragma unroll
      for (int reg = 0; reg < 4; ++reg) {
        int gr = row0 + wr + i * 16 + rq + reg;
        if (gr < Mr) {
          float v = acc[i][j][reg] + badd;
          if (STORE_F32) ((float*)Cout)[(size_t)gr * ldc + gc] = v;
          else           ((u16*)Cout)[(size_t)gr * ldc + gc] = f2bf(v);
        }
      }
    }
  }
}

// ---------- fused QKV GEMM: 256^2 tile, 16 waves (4x4), 4-deep ring ----------
// 1024 threads = 16 waves, per-wave C = 64x64 -> acc is 64 VGPR (4 waves/SIMD
// fits the register file; the 8-wave/128x64 shape was VGPR-bound at 2/SIMD).
// BK=32, counted vmcnt(4), ONE barrier/K-step, conflict-free chunks, coalesced
// staging. Epilogue batch/row split is division-free (one uniform div + wrap).
struct QkvSegs {
  const u16*   A[4];
  const u16*   Bw[4];
  const float* bias[4];
  int Mr[4], K[4], sl[4], obase[4], blk_end[4];
};
__global__ __launch_bounds__(1024) void gemm_qkv_seg(QkvSegs qs, u16* __restrict__ C) {
  __shared__ u16 lds[4][2][8192];          // [slot][A/B][16 chunks x 512] = 128 KiB
  int blk = blockIdx.x, seg = 0;
#pragma unroll
  for (int s = 0; s < 3; ++s) if (blk >= qs.blk_end[s]) seg = s + 1;
  const int base  = seg ? qs.blk_end[seg - 1] : 0;
  const int local = blk - base;
  const int cbt   = local % 12;            // col tile (12 x 256 = 3072)
  const int row0  = (local / 12) * 256;
  const int colL  = cbt * 256;
  const int Mr = qs.Mr[seg], K = qs.K[seg], sl = qs.sl[seg], obase = qs.obase[seg];
  const u16* A  = qs.A[seg];
  const u16* Bw = qs.Bw[seg];
  const float* bias = qs.bias[seg];

  const int tid  = threadIdx.x;
  const int lane = tid & 63;
  const int wave = tid >> 6;               // 0..15
  const int wm   = wave >> 2;              // 0..3
  const int wn   = wave & 3;               // 0..3

  // staging: wave w covers A rows [row0+w*16, +16) and B rows [colL+w*16, +16)
  const int srow = lane >> 2;
  const int soct = (((lane & 3) ^ ((lane >> 3) & 3))) << 3;
  int ra = row0 + wave * 16 + srow;  if (ra >= Mr) ra = Mr - 1;
  const u16* pA = A + (size_t)ra * K + soct;
  const u16* pB = Bw + (size_t)(colL + wave * 16 + srow) * K + soct;
  const int NS = K >> 5;                    // K-steps of 32

#define QSTAGE(slot, k0) do {                               \
    gll16(pA + (k0), (u16*)&lds[slot][0][wave * 512]);      \
    gll16(pB + (k0), (u16*)&lds[slot][1][wave * 512]);      \
  } while (0)

  f32x4 acc[4][4];
#pragma unroll
  for (int m = 0; m < 4; ++m)
#pragma unroll
    for (int n = 0; n < 4; ++n) acc[m][n] = f32x4{0.f, 0.f, 0.f, 0.f};

  // prologue: 3 tiles in flight (6 VMEM items/wave)
  QSTAGE(0, 0);
  QSTAGE(1, 32);
  QSTAGE(2, 64);

  const int fr  = lane & 15;
  const int fo  = lane >> 4;
  const int lrd = fr * 32 + (((fo ^ ((fr >> 1) & 3))) << 3);
  const int cam = wm * 4 * 512;            // A chunk base (u16)
  const int cbn = wn * 4 * 512;            // B chunk base (u16)

#pragma unroll 4
  for (int s = 0; s < NS; ++s) {
    // certify tile s landed: keep tiles s+1, s+2 (4 items) in flight
    asm volatile("s_waitcnt vmcnt(4)" ::: "memory");
    __builtin_amdgcn_s_barrier();
    asm volatile("" ::: "memory");         // no loads/stages above the barrier

    const u16* Ab = &lds[s & 3][0][0];
    const u16* Bb = &lds[s & 3][1][0];
    bf16x8 af[4], bf[4];
#pragma unroll
    for (int n = 0; n < 4; ++n)
      bf[n] = *(const bf16x8*)&Bb[cbn + n * 512 + lrd];
#pragma unroll
    for (int m = 0; m < 4; ++m)
      af[m] = *(const bf16x8*)&Ab[cam + m * 512 + lrd];

    // prefetch tile s+3 into slot (s-1)&3 (freed by the barrier above);
    // past the end: clamped dummy re-stage keeps the vmcnt count uniform.
    const int s3 = s + 3;
    const int k3 = (s3 < NS ? s3 : NS - 1) << 5;
    QSTAGE(s3 & 3, k3);

#pragma unroll
    for (int m = 0; m < 4; ++m)
#pragma unroll
      for (int n = 0; n < 4; ++n)
        acc[m][n] = __builtin_amdgcn_mfma_f32_16x16x32_bf16(af[m], bf[n], acc[m][n], 0, 0, 0);
  }
#undef QSTAGE

  asm volatile("s_waitcnt vmcnt(0)" ::: "memory");

  // epilogue: packed-row write; C/D layout col = lane&15, row = (lane>>4)*4 + reg.
  // Division-free batch split: one uniform div, then wrap (span 64 <= sl).
  const int fc = lane & 15;
  const int rq = (lane >> 4) * 4;
  const int u0  = row0 + wm * 64;          // wave-uniform
  const int bb0 = u0 / sl;
  const int ss0 = u0 - bb0 * sl;
#pragma unroll
  for (int m = 0; m < 4; ++m) {
#pragma unroll
    for (int n = 0; n < 4; ++n) {
      const int cl = wn * 64 + n * 16 + fc;
      const float badd = bias[colL + cl];
      const int gc = colL + cl;
#pragma unroll
      for (int reg = 0; reg < 4; ++reg) {
        const int off = m * 16 + rq + reg;       // 0..63
        if (u0 + off < Mr) {
          int ss = ss0 + off, bb = bb0;
          if (ss >= sl) { ss -= sl; ++bb; }
          C[(size_t)(bb * RPB + obase + ss) * 3072 + gc] = f2bf(acc[m][n][reg] + badd);
        }
      }
    }
  }
}

// ---------- windowed attention + mean over modalities ----------
// ROUTES (IEEE-tie-corrected Cantor): m0:[0,1,2] m1:[0,1,2] m2:[2,3,0] m3:[3,2,0]
__global__ __launch_bounds__(256) void attn_fuse(
    const u16* __restrict__ QKV,   // [RROWS][3072]: Q|K|V
    u16* __restrict__ fused,
    const float* __restrict__ bq, const float* __restrict__ bk, const float* __restrict__ bv,
    const float* __restrict__ temp_ptr)
{
  const int ROUTE[4][3] = {{0,1,2},{0,1,2},{2,3,0},{3,2,0}};
  const int SLm[4]  = {SL0, SL1, SL2, SL3};
  const int OFFS[4] = {0, 2048, 3072, 4572};
  const int tid  = threadIdx.x;
  const int lane = tid & 63;
  const int wave = tid >> 6;
  const int bs   = blockIdx.x * 2 + (wave >> 1);
  const int s    = bs & 2047;
  const int b    = bs >> 11;
  const int h    = (wave & 1) * 8 + (lane >> 3);
  const int sub  = lane & 7;
  const int dbase = h * 64 + sub * 8;
  const float scale = 1.0f / (8.0f * fabsf(temp_ptr[0]));

  float qf[4][8], kf[4][8], vf[4][8];
#pragma unroll
  for (int r = 0; r < 4; ++r) {
    if (s < SLm[r]) {
      const u16* base = QKV + ((size_t)(b * RPB + OFFS[r] + s)) * 3072 + dbase;
      u16x8 q8 = *(const u16x8*)(base);
      u16x8 k8 = *(const u16x8*)(base + 1024);
      u16x8 v8 = *(const u16x8*)(base + 2048);
#pragma unroll
      for (int i = 0; i < 8; ++i) {
        qf[r][i] = bf2f(q8[i]); kf[r][i] = bf2f(k8[i]); vf[r][i] = bf2f(v8[i]);
      }
    } else {
#pragma unroll
      for (int i = 0; i < 8; ++i) {
        qf[r][i] = bq[dbase + i]; kf[r][i] = bk[dbase + i]; vf[r][i] = bv[dbase + i];
      }
    }
  }

  float acc[8];
#pragma unroll
  for (int i = 0; i < 8; ++i) acc[i] = 0.f;

#pragma unroll
  for (int m = 0; m < 4; ++m) {
    float sc[3];
#pragma unroll
    for (int w = 0; w < 3; ++w) {
      const int r = ROUTE[m][w];
      float d = 0.f;
#pragma unroll
      for (int i = 0; i < 8; ++i) d += qf[m][i] * kf[r][i];
      d += __shfl_xor(d, 1, 64);
      d += __shfl_xor(d, 2, 64);
      d += __shfl_xor(d, 4, 64);
      sc[w] = d * scale;
    }
    float mx = fmaxf(sc[0], fmaxf(sc[1], sc[2]));
    float e0 = __expf(sc[0] - mx), e1 = __expf(sc[1] - mx), e2 = __expf(sc[2] - mx);
    float inv = 1.0f / (e0 + e1 + e2);
    float ws[3] = {e0 * inv, e1 * inv, e2 * inv};
#pragma unroll
    for (int w = 0; w < 3; ++w) {
      const int r = ROUTE[m][w];
#pragma unroll
      for (int i = 0; i < 8; ++i) acc[i] += ws[w] * vf[r][i];
    }
  }
  u16x8 o;
#pragma unroll
  for (int i = 0; i < 8; ++i) o[i] = f2bf(acc[i] * 0.25f);
  *(u16x8*)(fused + (size_t)bs * 1024 + dbase) = o;
}

// ---------- host orchestration ----------
extern "C" void kernel_launch(void* const* d_in, const int* in_sizes, int n_in,
                              void* d_out, int out_size, void* d_ws, size_t ws_size,
                              hipStream_t stream) {
  const int B = 4, S = 2048, D = 1024;
  const int SL[4]   = {SL0, SL1, SL2, SL3};
  const int DIM[4]  = {768, 1024, 512, 2048};
  const int OFFS[4] = {0, 2048, 3072, 4572};

  const float* x[4]  = {(const float*)d_in[0], (const float*)d_in[3], (const float*)d_in[6], (const float*)d_in[9]};
  const float* Wm[4] = {(const float*)d_in[1], (const float*)d_in[4], (const float*)d_in[7], (const float*)d_in[10]};
  const float* bm[4] = {(const float*)d_in[2], (const float*)d_in[5], (const float*)d_in[8], (const float*)d_in[11]};
  const float* mod_emb = (const float*)d_in[12];
  const float* Wq = (const float*)d_in[13]; const float* bq = (const float*)d_in[14];
  const float* Wk = (const float*)d_in[15]; const float* bk = (const float*)d_in[16];
  const float* Wv = (const float*)d_in[17]; const float* bv = (const float*)d_in[18];
  const float* Wo = (const float*)d_in[19]; const float* bo = (const float*)d_in[20];
  const float* temp = (const float*)d_in[21];

  const int RROWS = B * RPB;                 // 20336 real rows
  const size_t qkvB   = ((size_t)RROWS * 3 * D * 2 + 255) / 256 * 256;
  size_t xbB[4], wmTB[4], wqkvmB[4];
  size_t xbTot = 0, wmTTot = 0, wqkvmTot = 0;
  for (int m = 0; m < 4; ++m) {
    xbB[m]    = ((size_t)B * SL[m] * DIM[m] * 2 + 255) / 256 * 256;  xbTot    += xbB[m];
    wmTB[m]   = ((size_t)DIM[m] * D * 2 + 255) / 256 * 256;          wmTTot   += wmTB[m];
    wqkvmB[m] = ((size_t)3 * D * DIM[m] * 2 + 255) / 256 * 256;      wqkvmTot += wqkvmB[m];
  }
  const size_t wB   = (size_t)D * D * 2;     // exactly 2 MB, keeps wq|wk|wv contiguous
  const size_t bqmB = ((size_t)4 * 3 * D * 4 + 255) / 256 * 256;
  const size_t need = qkvB + xbTot + wmTTot + 3 * wB + wB + wqkvmTot + bqmB;
  if (ws_size < need) return;                // clean failure, not OOB crash

  char* p = (char*)d_ws;
  u16* qkv = (u16*)p;  p += qkvB;
  u16* xb[4];
  char* xbBase = p;
  for (int m = 0; m < 4; ++m) { xb[m] = (u16*)p; p += xbB[m]; }
  u16* wmT[4];
  for (int m = 0; m < 4; ++m) { wmT[m] = (u16*)p; p += wmTB[m]; }
  u16* wqb = (u16*)p;  p += wB;              // wq|wk|wv contiguous = [3072][1024]
  u16* wkb = (u16*)p;  p += wB;
  u16* wvb = (u16*)p;  p += wB;
  u16* wob = (u16*)p;  p += wB;
  u16* wqkvm[4];
  for (int m = 0; m < 4; ++m) { wqkvm[m] = (u16*)p; p += wqkvmB[m]; }
  float* bqm = (float*)p;  p += bqmB;
  u16* fusedb = (u16*)xbBase;                // xb dead after QKV GEMM

  // merged prep: flat cvt (X + Wq,Wk,Wv,Wo) | Wm transpose | fused bias
  {
    PrepAll pa;
    const float* csrcs[8] = {x[0], x[1], x[2], x[3], Wq, Wk, Wv, Wo};
    u16* cdsts[8] = {xb[0], xb[1], xb[2], xb[3], wqb, wkb, wvb, wob};
    int ns[8];
    for (int m = 0; m < 4; ++m) ns[m] = B * SL[m] * DIM[m];
    for (int i = 0; i < 4; ++i) ns[4 + i] = D * D;
    int cbase = 0;
    for (int i = 0; i < 8; ++i) {
      pa.csrc[i] = csrcs[i]; pa.cdst[i] = cdsts[i];
      pa.cbase[i] = cbase;
      cbase += (ns[i] + 1023) / 1024;
      pa.cend[i] = cbase;
    }
    pa.cvtN = cbase;
    int tb = 0;
    for (int m = 0; m < 4; ++m) {
      pa.tsrc[m] = Wm[m]; pa.tdst[m] = wmT[m]; pa.tdim[m] = DIM[m];
      tb += (D / 32) * (DIM[m] / 32);
      pa.tend[m] = tb;
    }
    pa.trN = tb;
    pa.Wq = Wq; pa.Wk = Wk; pa.Wv = Wv;
    pa.bq = bq; pa.bk = bk; pa.bv = bv;
    pa.bm0 = bm[0]; pa.bm1 = bm[1]; pa.bm2 = bm[2]; pa.bm3 = bm[3];
    pa.emb = mod_emb; pa.bout = bqm;
    prep_all<<<pa.cvtN + pa.trN + 3072, 256, 0, stream>>>(pa);
  }

  // weight prep: Wqkvm[m] = [Wq;Wk;Wv] @ Wm[m]  -> bf16 [3072][DIM[m]]
  {
    const int ord[4] = {3, 1, 0, 2};   // by descending N: 2048,1024,768,512
    WpSegs wsg;
    int base = 0;
    for (int i = 0; i < 4; ++i) {
      int m = ord[i];
      wsg.Bw[i] = wmT[m]; wsg.Cout[i] = wqkvm[m]; wsg.Nn[i] = DIM[m];
      base += (3 * D / 128) * (DIM[m] / 128);
      wsg.blk_end[i] = base;
    }
    gemm_wprep<<<base, 256, 0, stream>>>(wsg, wqb);
  }

  // fused QKV GEMM: qkv rows = X @ Wqkvm^T + bqm (per modality, packed rows)
  {
    const int ord[4] = {3, 1, 0, 2};   // by descending K: 2048,1024,768,512
    QkvSegs qsg;
    int base = 0;
    for (int i = 0; i < 4; ++i) {
      int m = ord[i];
      int Mr = B * SL[m];
      qsg.A[i] = xb[m]; qsg.Bw[i] = wqkvm[m]; qsg.bias[i] = bqm + m * 3072;
      qsg.Mr[i] = Mr; qsg.K[i] = DIM[m]; qsg.sl[i] = SL[m]; qsg.obase[i] = OFFS[m];
      base += 12 * ((Mr + 255) / 256);
      qsg.blk_end[i] = base;
    }
    gemm_qkv_seg<<<base, 1024, 0, stream>>>(qsg, qkv);
  }

  // attention over window + mean over modalities -> fused (bf16, overlays xb)
  attn_fuse<<<(B * S) / 2, 256, 0, stream>>>(qkv, fusedb, bq, bk, bv, temp);

  // output GEMM: (B*S) x D, fp32 out
  {
    dim3 grid(8, (B * S) / 128);
    gemm_lds<1><<<grid, 256, 0, stream>>>(fusedb, wob, wob, wob, bo, bo, bo,
                                          d_out, B * S, D, D);
  }
}